// Round 1
// baseline (13817.747 us; speedup 1.0000x reference)
//
#include <hip/hip_runtime.h>

typedef float f4 __attribute__((ext_vector_type(4)));

constexpr int Bn = 4, Tn = 1024, Dn = 512, CAPn = 32768, Kn = 1024;
constexpr int ROWS = Bn * Tn; // 4096
constexpr float SCALE = 0.044194173824159216f; // 1/sqrt(512)
constexpr float MOM = 0.99f;
constexpr float RATE_B = 0.0025f; // 0.01 / B

// ---- workspace layout (float offsets). Total ~97.3 MiB ----
constexpr size_t OFF_NEWMEM  = 0;                                   // CAP*D
constexpr size_t OFF_OUTPART = OFF_NEWMEM + (size_t)CAPn * Dn;      // 4*ROWS*D
constexpr size_t OFF_L1PART  = OFF_OUTPART + (size_t)4 * ROWS * Dn; // ROWS*8
constexpr size_t OFF_INVL1   = OFF_L1PART + (size_t)ROWS * 8;       // ROWS
constexpr size_t OFF_L2PART  = OFF_INVL1 + ROWS;                    // ROWS*8
constexpr size_t OFF_INVL2   = OFF_L2PART + (size_t)ROWS * 8;       // ROWS
constexpr size_t OFF_PRIO    = OFF_INVL2 + ROWS;                    // B*CAP
constexpr size_t OFF_COMB    = OFF_PRIO + (size_t)Bn * CAPn;        // 16 (pad)
constexpr size_t OFF_RANK    = OFF_COMB + 16;                       // B*CAP ints

// XOR swizzle inside a 64x64 f32 LDS tile: phys offset for (row, col).
// Spreads stride-64 column walks across bank groups (<=2-way, free per m136).
__device__ __forceinline__ int sw(int r, int c) {
  return (r << 6) + (c ^ (((r >> 2) & 7) << 2));
}

// Computes acc[4][4] = A[rowBase+ty*4+i, :] . M[cBase+tx*4+j, :] over K=512.
__device__ __forceinline__ void gemm_tile(const float* __restrict__ A,
                                          const float* __restrict__ M,
                                          int rowBase, int cBase, int tid,
                                          float* As, float* Ms, float acc[4][4]) {
  const int tx = tid & 15, ty = tid >> 4;
#pragma unroll
  for (int i = 0; i < 4; ++i)
#pragma unroll
    for (int j = 0; j < 4; ++j) acc[i][j] = 0.f;
  for (int kk = 0; kk < Dn; kk += 64) {
#pragma unroll
    for (int it = 0; it < 4; ++it) {
      int idx = tid + it * 256;
      int r = idx >> 4, c4 = (idx & 15) << 2;
      *(f4*)&As[sw(r, c4)] = *(const f4*)&A[(size_t)(rowBase + r) * Dn + kk + c4];
      *(f4*)&Ms[sw(r, c4)] = *(const f4*)&M[(size_t)(cBase + r) * Dn + kk + c4];
    }
    __syncthreads();
#pragma unroll
    for (int k4 = 0; k4 < 16; ++k4) {
      f4 a[4], m[4];
#pragma unroll
      for (int i = 0; i < 4; ++i) a[i] = *(f4*)&As[sw(ty * 4 + i, k4 * 4)];
#pragma unroll
      for (int j = 0; j < 4; ++j) m[j] = *(f4*)&Ms[sw(tx * 4 + j, k4 * 4)];
#pragma unroll
      for (int i = 0; i < 4; ++i)
#pragma unroll
        for (int j = 0; j < 4; ++j) {
          acc[i][j] += a[i][0] * m[j][0];
          acc[i][j] += a[i][1] * m[j][1];
          acc[i][j] += a[i][2] * m[j][2];
          acc[i][j] += a[i][3] * m[j][3];
        }
    }
    __syncthreads();
  }
}

// combined[b] = mean(importance[b,:,0])
__global__ void k_combined(const float* __restrict__ imp, float* __restrict__ comb) {
  __shared__ float red[256];
  int b = blockIdx.x;
  float s = 0.f;
  for (int t = threadIdx.x; t < Tn; t += 256) s += imp[(size_t)b * Tn + t];
  red[threadIdx.x] = s;
  __syncthreads();
  for (int off = 128; off > 0; off >>= 1) {
    if (threadIdx.x < (unsigned)off) red[threadIdx.x] += red[threadIdx.x + off];
    __syncthreads();
  }
  if (threadIdx.x == 0) comb[b] = red[0] * (1.0f / Tn);
}

// Partial softmax denominators: lpart[row, chunk] = sum_{c in chunk} exp(s*scale?)
template <bool SC>
__global__ __launch_bounds__(256) void k_rowexp(const float* __restrict__ A,
                                                const float* __restrict__ M,
                                                float* __restrict__ lpart) {
  __shared__ float As[64 * 64], Ms[64 * 64];
  const int tid = threadIdx.x, tx = tid & 15, ty = tid >> 4;
  const int rowBase = blockIdx.x * 64;
  const int chunk = blockIdx.y; // 8 chunks of CAP/8
  float lacc[4] = {0.f, 0.f, 0.f, 0.f};
  for (int ct = 0; ct < CAPn / 8; ct += 64) {
    float acc[4][4];
    gemm_tile(A, M, rowBase, chunk * (CAPn / 8) + ct, tid, As, Ms, acc);
#pragma unroll
    for (int i = 0; i < 4; ++i) {
      float s = 0.f;
#pragma unroll
      for (int j = 0; j < 4; ++j) s += __expf(SC ? acc[i][j] * SCALE : acc[i][j]);
      lacc[i] += s;
    }
  }
#pragma unroll
  for (int i = 0; i < 4; ++i) {
    float v = lacc[i];
#pragma unroll
    for (int off = 8; off > 0; off >>= 1) v += __shfl_down(v, off, 16);
    if (tx == 0) lpart[(size_t)(rowBase + ty * 4 + i) * 8 + chunk] = v;
  }
}

__global__ void k_invl(const float* __restrict__ lpart, float* __restrict__ invl) {
  int r = blockIdx.x * 256 + threadIdx.x;
  float s = 0.f;
#pragma unroll
  for (int ch = 0; ch < 8; ++ch) s += lpart[(size_t)r * 8 + ch];
  invl[r] = 1.0f / s;
}

// prio[b,c] = combined[b] + 0.1 * sum_t exp(scores[b,t,c]) * invl[b,t]
__global__ __launch_bounds__(256) void k_usage(const float* __restrict__ keys,
                                               const float* __restrict__ M,
                                               const float* __restrict__ invl,
                                               const float* __restrict__ comb,
                                               float* __restrict__ prio) {
  __shared__ float As[64 * 64], Ms[64 * 64];
  __shared__ float red[16][64];
  const int tid = threadIdx.x, tx = tid & 15, ty = tid >> 4;
  const int cBase = blockIdx.x * 64;
  const int b = blockIdx.y;
  float uacc[4] = {0.f, 0.f, 0.f, 0.f};
  for (int tt = 0; tt < Tn; tt += 64) {
    const int rowBase = b * Tn + tt;
    float acc[4][4];
    gemm_tile(keys, M, rowBase, cBase, tid, As, Ms, acc);
#pragma unroll
    for (int i = 0; i < 4; ++i) {
      float il = invl[rowBase + ty * 4 + i];
#pragma unroll
      for (int j = 0; j < 4; ++j) uacc[j] += __expf(acc[i][j]) * il;
    }
  }
#pragma unroll
  for (int j = 0; j < 4; ++j) red[ty][tx * 4 + j] = uacc[j];
  __syncthreads();
  for (int off = 8; off > 0; off >>= 1) {
    if (ty < off) {
#pragma unroll
      for (int j = 0; j < 4; ++j) red[ty][tx * 4 + j] += red[ty + off][tx * 4 + j];
    }
    __syncthreads();
  }
  if (tid < 64) prio[(size_t)b * CAPn + cBase + tid] = comb[b] + 0.1f * red[0][tid];
}

// rank[b,c] = #{c' : prio[c'] > prio[c] or (== and c' < c)}  (jax top_k stable order)
__global__ __launch_bounds__(256) void k_rank(const float* __restrict__ prio,
                                              int* __restrict__ rank) {
  const int b = blockIdx.y;
  const int c = blockIdx.x * 256 + threadIdx.x;
  const float* p = prio + (size_t)b * CAPn;
  unsigned mb = __float_as_uint(p[c]);
  mb = (mb & 0x80000000u) ? ~mb : (mb | 0x80000000u);
  unsigned long long mykey =
      ((unsigned long long)mb << 32) | (unsigned)(0xFFFFFFFFu - c);
  __shared__ unsigned long long tile[2048];
  int cnt = 0;
  for (int base = 0; base < CAPn; base += 2048) {
    __syncthreads();
    for (int i = threadIdx.x; i < 2048; i += 256) {
      unsigned ub = __float_as_uint(p[base + i]);
      ub = (ub & 0x80000000u) ? ~ub : (ub | 0x80000000u);
      tile[i] = ((unsigned long long)ub << 32) | (unsigned)(0xFFFFFFFFu - (base + i));
    }
    __syncthreads();
#pragma unroll 8
    for (int i = 0; i < 2048; ++i) cnt += (tile[i] > mykey) ? 1 : 0;
  }
  rank[(size_t)b * CAPn + c] = cnt;
}

// new_mem = 0.99*mem + 0.0025 * sum_b (rank_b[c] < K ? values[b, rank_b[c], :] : 0)
__global__ void k_newmem(const float* __restrict__ mem, const float* __restrict__ values,
                         const int* __restrict__ rank, float* __restrict__ newmem) {
  int gid = blockIdx.x * 256 + threadIdx.x;
  int c = gid >> 7;          // D/4 = 128 quads per row
  int q = (gid & 127) << 2;  // d offset
  f4 m = *(const f4*)&mem[(size_t)c * Dn + q];
  f4 acc = {0.f, 0.f, 0.f, 0.f};
#pragma unroll
  for (int b = 0; b < Bn; ++b) {
    int r = rank[(size_t)b * CAPn + c];
    if (r < Kn) {
      f4 v = *(const f4*)&values[((size_t)b * Tn + r) * Dn + q];
      acc += v;
    }
  }
  f4 res = m * MOM + acc * RATE_B;
  *(f4*)&newmem[(size_t)c * Dn + q] = res;
}

// out partials: for c-chunk, outpart[chunk][row][d] = sum_{c in chunk} p * new_mem[c,d]
__global__ __launch_bounds__(256) void k_attnout(const float* __restrict__ Q,
                                                 const float* __restrict__ M,
                                                 const float* __restrict__ invl,
                                                 float* __restrict__ outpart) {
  __shared__ float As[64 * 64], Ms[64 * 64], Ps[64 * 64];
  const int tid = threadIdx.x, tx = tid & 15, ty = tid >> 4;
  const int rowBase = blockIdx.x * 64;
  const int chunk = blockIdx.y; // 4 chunks of 8192
  float o[4][8][4] = {};
  float il[4];
#pragma unroll
  for (int i = 0; i < 4; ++i) il[i] = invl[rowBase + ty * 4 + i];
  for (int ct = 0; ct < 8192; ct += 64) {
    const int cBase = chunk * 8192 + ct;
    float acc[4][4];
    gemm_tile(Q, M, rowBase, cBase, tid, As, Ms, acc);
#pragma unroll
    for (int i = 0; i < 4; ++i) {
      f4 pv;
#pragma unroll
      for (int j = 0; j < 4; ++j) pv[j] = __expf(acc[i][j] * SCALE) * il[i];
      *(f4*)&Ps[sw(ty * 4 + i, tx * 4)] = pv;
    }
    __syncthreads();
#pragma unroll
    for (int dc = 0; dc < 8; ++dc) {
#pragma unroll
      for (int it = 0; it < 4; ++it) {
        int idx = tid + it * 256;
        int r = idx >> 4, c4 = (idx & 15) << 2;
        *(f4*)&Ms[sw(r, c4)] = *(const f4*)&M[(size_t)(cBase + r) * Dn + dc * 64 + c4];
      }
      __syncthreads();
#pragma unroll
      for (int c4 = 0; c4 < 16; ++c4) {
        f4 p[4], m[4];
#pragma unroll
        for (int i = 0; i < 4; ++i) p[i] = *(f4*)&Ps[sw(ty * 4 + i, c4 * 4)];
#pragma unroll
        for (int u = 0; u < 4; ++u) m[u] = *(f4*)&Ms[sw(c4 * 4 + u, tx * 4)];
#pragma unroll
        for (int i = 0; i < 4; ++i)
#pragma unroll
          for (int j = 0; j < 4; ++j) {
            o[i][dc][j] += p[i][0] * m[0][j];
            o[i][dc][j] += p[i][1] * m[1][j];
            o[i][dc][j] += p[i][2] * m[2][j];
            o[i][dc][j] += p[i][3] * m[3][j];
          }
      }
      __syncthreads();
    }
  }
#pragma unroll
  for (int i = 0; i < 4; ++i)
#pragma unroll
    for (int dc = 0; dc < 8; ++dc) {
      f4 v;
#pragma unroll
      for (int j = 0; j < 4; ++j) v[j] = o[i][dc][j];
      *(f4*)&outpart[(((size_t)chunk * ROWS) + rowBase + ty * 4 + i) * Dn + dc * 64 +
                     tx * 4] = v;
    }
}

__global__ void k_merge(const float* __restrict__ outpart, float* __restrict__ out) {
  size_t q = ((size_t)blockIdx.x * 256 + threadIdx.x) * 4;
  f4 s = *(const f4*)&outpart[q];
#pragma unroll
  for (int ch = 1; ch < 4; ++ch) s += *(const f4*)&outpart[(size_t)ch * ROWS * Dn + q];
  *(f4*)&out[q] = s;
}

extern "C" void kernel_launch(void* const* d_in, const int* in_sizes, int n_in,
                              void* d_out, int out_size, void* d_ws, size_t ws_size,
                              hipStream_t stream) {
  const float* keys = (const float*)d_in[0];
  const float* values = (const float*)d_in[1];
  const float* importance = (const float*)d_in[2];
  const float* query = (const float*)d_in[3];
  const float* mem = (const float*)d_in[4];
  float* ws = (float*)d_ws;
  float* newmem = ws + OFF_NEWMEM;
  float* outpart = ws + OFF_OUTPART;
  float* l1part = ws + OFF_L1PART;
  float* invl1 = ws + OFF_INVL1;
  float* l2part = ws + OFF_L2PART;
  float* invl2 = ws + OFF_INVL2;
  float* prio = ws + OFF_PRIO;
  float* comb = ws + OFF_COMB;
  int* rank = (int*)(ws + OFF_RANK);
  float* out = (float*)d_out;

  k_combined<<<Bn, 256, 0, stream>>>(importance, comb);
  k_rowexp<false><<<dim3(ROWS / 64, 8), 256, 0, stream>>>(keys, mem, l1part);
  k_invl<<<ROWS / 256, 256, 0, stream>>>(l1part, invl1);
  k_usage<<<dim3(CAPn / 64, Bn), 256, 0, stream>>>(keys, mem, invl1, comb, prio);
  k_rank<<<dim3(CAPn / 256, Bn), 256, 0, stream>>>(prio, rank);
  k_newmem<<<(CAPn * Dn / 4) / 256, 256, 0, stream>>>(mem, values, rank, newmem);
  k_rowexp<true><<<dim3(ROWS / 64, 8), 256, 0, stream>>>(query, newmem, l2part);
  k_invl<<<ROWS / 256, 256, 0, stream>>>(l2part, invl2);
  k_attnout<<<dim3(ROWS / 64, 4), 256, 0, stream>>>(query, newmem, invl2, outpart);
  k_merge<<<(ROWS * Dn / 4) / 256, 256, 0, stream>>>(outpart, out);
}

// Round 2
// 2925.786 us; speedup vs baseline: 4.7227x; 4.7227x over previous
//
#include <hip/hip_runtime.h>

typedef float f32x4 __attribute__((ext_vector_type(4)));
typedef short s16x8 __attribute__((ext_vector_type(8)));
typedef short s16x4 __attribute__((ext_vector_type(4)));
typedef unsigned short ush;

constexpr int Bn = 4, Tn = 1024, Dn = 512, CAPn = 32768, Kn = 1024;
constexpr int ROWS = Bn * Tn; // 4096
constexpr float SCALE = 0.044194173824159216f; // 1/sqrt(512)
constexpr float MOM = 0.99f;
constexpr float RATE_B = 0.0025f; // 0.01 / B

// ---- workspace layout (byte offsets). Total ~97.6 MB (proven ws >= 102.0 MB) ----
constexpr size_t OFF_NM    = 0;                                  // ush [CAP][D]   (aliased: mem_lo before k_newmem)
constexpr size_t OFF_NMT   = OFF_NM  + (size_t)CAPn * Dn * 2;    // ush [D][CAP]   (aliased: mem_hi before k_nmT)
constexpr size_t OFF_KHI   = OFF_NMT + (size_t)Dn * CAPn * 2;    // ush [ROWS][D]
constexpr size_t OFF_KLO   = OFF_KHI + (size_t)ROWS * Dn * 2;
constexpr size_t OFF_QBF   = OFF_KLO + (size_t)ROWS * Dn * 2;
constexpr size_t OFF_OPART = OFF_QBF + (size_t)ROWS * Dn * 2;    // ush [2][ROWS][D]
constexpr size_t OFF_ZPART = OFF_OPART + (size_t)2 * ROWS * Dn * 2; // f32 [512][ROWS]
constexpr size_t OFF_INVL1 = OFF_ZPART + (size_t)512 * ROWS * 4;
constexpr size_t OFF_INVL2 = OFF_INVL1 + (size_t)ROWS * 4;
constexpr size_t OFF_PRIO  = OFF_INVL2 + (size_t)ROWS * 4;       // f32 [4][CAP]
constexpr size_t OFF_RANK  = OFF_PRIO + (size_t)Bn * CAPn * 4;   // i32 [4][CAP]
constexpr size_t OFF_COMB  = OFF_RANK + (size_t)Bn * CAPn * 4;   // f32 [4]

#define MFMA(a, b, c) __builtin_amdgcn_mfma_f32_16x16x32_bf16((a), (b), (c), 0, 0, 0)

__device__ __forceinline__ ush bfrn(float x) {
  unsigned u = __float_as_uint(x);
  return (ush)((u + 0x7FFFu + ((u >> 16) & 1u)) >> 16);
}
__device__ __forceinline__ float bff(ush h) { return __uint_as_float(((unsigned)h) << 16); }

// combined[b] = mean(importance[b,:,0])
__global__ void k_combined(const float* __restrict__ imp, float* __restrict__ comb) {
  __shared__ float red[256];
  int b = blockIdx.x;
  float s = 0.f;
  for (int t = threadIdx.x; t < Tn; t += 256) s += imp[(size_t)b * Tn + t];
  red[threadIdx.x] = s;
  __syncthreads();
  for (int off = 128; off > 0; off >>= 1) {
    if (threadIdx.x < (unsigned)off) red[threadIdx.x] += red[threadIdx.x + off];
    __syncthreads();
  }
  if (threadIdx.x == 0) comb[b] = red[0] * (1.0f / Tn);
}

// x -> hi (RTN bf16), lo (RTN bf16 of residual). 4 elems/thread.
__global__ void k_cvt_hilo(const float* __restrict__ x, ush* __restrict__ hi,
                           ush* __restrict__ lo) {
  size_t i = ((size_t)blockIdx.x * 256 + threadIdx.x) * 4;
  f32x4 v = *(const f32x4*)&x[i];
  s16x4 h, l;
#pragma unroll
  for (int j = 0; j < 4; ++j) {
    ush hh = bfrn(v[j]);
    h[j] = (short)hh;
    l[j] = (short)bfrn(v[j] - bff(hh));
  }
  *(s16x4*)&hi[i] = h;
  *(s16x4*)&lo[i] = l;
}

__global__ void k_cvt_bf(const float* __restrict__ x, ush* __restrict__ o) {
  size_t i = ((size_t)blockIdx.x * 256 + threadIdx.x) * 4;
  f32x4 v = *(const f32x4*)&x[i];
  s16x4 h;
#pragma unroll
  for (int j = 0; j < 4; ++j) h[j] = (short)bfrn(v[j]);
  *(s16x4*)&o[i] = h;
}

// Z partials: zpart[cb][t] = sum over this block's 64 c of exp(A[c,:].B[t,:] (*SCALE))
// A rows held in registers (bf16), B tiles staged full-K in LDS.
template <bool SC>
__global__ __launch_bounds__(256, 2) void k_rowexp(const ush* __restrict__ Abf,
                                                   const ush* __restrict__ Bbf,
                                                   float* __restrict__ zpart) {
  __shared__ ush Bs[64 * 512];
  __shared__ float red[2][64];
  const int tid = threadIdx.x;
  const int lane = tid & 63, wid = tid >> 6;
  const int wc2 = wid >> 1, wt = wid & 1;
  const int l15 = lane & 15, g = lane >> 4;
  const int cb = blockIdx.x;
  const int cBase = cb * 64;

  s16x8 afr[2][16];
#pragma unroll
  for (int mi = 0; mi < 2; ++mi) {
    int c = cBase + wc2 * 32 + mi * 16 + l15;
#pragma unroll
    for (int ks = 0; ks < 16; ++ks)
      afr[mi][ks] = *(const s16x8*)&Abf[(size_t)c * Dn + ks * 32 + g * 8];
  }

  for (int tt = 0; tt < 64; ++tt) {
    const int tBase = tt * 64;
#pragma unroll
    for (int rr = 0; rr < 16; ++rr) {
      int idx = rr * 256 + tid;
      int row = idx >> 6, ch = idx & 63;
      s16x8 v = *(const s16x8*)&Bbf[(size_t)(tBase + row) * Dn + ch * 8];
      *(s16x8*)&Bs[row * 512 + ((ch ^ (row & 7)) * 8)] = v;
    }
    __syncthreads();
    f32x4 S[2][2];
#pragma unroll
    for (int mi = 0; mi < 2; ++mi)
#pragma unroll
      for (int ni = 0; ni < 2; ++ni) S[mi][ni] = (f32x4){0.f, 0.f, 0.f, 0.f};
#pragma unroll
    for (int ks = 0; ks < 16; ++ks) {
      s16x8 bfr[2];
#pragma unroll
      for (int ni = 0; ni < 2; ++ni) {
        int trow = wt * 32 + ni * 16 + l15;
        bfr[ni] = *(const s16x8*)&Bs[trow * 512 + (((ks * 4 + g) ^ (trow & 7)) * 8)];
      }
#pragma unroll
      for (int mi = 0; mi < 2; ++mi)
#pragma unroll
        for (int ni = 0; ni < 2; ++ni) S[mi][ni] = MFMA(afr[mi][ks], bfr[ni], S[mi][ni]);
    }
    float tacc[2] = {0.f, 0.f};
#pragma unroll
    for (int mi = 0; mi < 2; ++mi)
#pragma unroll
      for (int ni = 0; ni < 2; ++ni)
#pragma unroll
        for (int r = 0; r < 4; ++r)
          tacc[ni] += __expf(SC ? S[mi][ni][r] * SCALE : S[mi][ni][r]);
#pragma unroll
    for (int ni = 0; ni < 2; ++ni) {
      float v = tacc[ni];
      v += __shfl_xor(v, 16);
      v += __shfl_xor(v, 32);
      tacc[ni] = v;
    }
    if (g == 0) {
      red[wc2][wt * 32 + l15] = tacc[0];
      red[wc2][wt * 32 + 16 + l15] = tacc[1];
    }
    __syncthreads();
    if (tid < 64) zpart[(size_t)cb * ROWS + tBase + tid] = red[0][tid] + red[1][tid];
  }
}

__global__ void k_invl(const float* __restrict__ zpart, float* __restrict__ invl) {
  int t = blockIdx.x * 256 + threadIdx.x;
  float s = 0.f;
  for (int cb = 0; cb < 512; ++cb) s += zpart[(size_t)cb * ROWS + t];
  invl[t] = 1.0f / s;
}

// prio[b,c] = comb[b] + 0.1 * sum_t exp(scores[b,t,c]) * invl1[b,t]
// 3-term compensated bf16 GEMM (hi*hi + hi*lo + lo*hi). Block: 128 c, full t loop.
__global__ __launch_bounds__(256, 2) void k_usage(const ush* __restrict__ mhi,
                                                  const ush* __restrict__ mlo,
                                                  const ush* __restrict__ khi,
                                                  const ush* __restrict__ klo,
                                                  const float* __restrict__ invl,
                                                  const float* __restrict__ comb,
                                                  float* __restrict__ prio) {
  __shared__ ush Ahi[128 * 64], Alo[128 * 64], Bhi[128 * 64], Blo[128 * 64];
  const int tid = threadIdx.x;
  const int lane = tid & 63, w = tid >> 6;
  const int l15 = lane & 15, g = lane >> 4;
  const int cBase = blockIdx.x * 128;
  const int b = blockIdx.y;
  const ush* khb = khi + (size_t)b * Tn * Dn;
  const ush* klb = klo + (size_t)b * Tn * Dn;

  float uacc[2][4] = {{0.f, 0.f, 0.f, 0.f}, {0.f, 0.f, 0.f, 0.f}};
  for (int tt = 0; tt < 8; ++tt) {
    f32x4 S[2][8];
#pragma unroll
    for (int mi = 0; mi < 2; ++mi)
#pragma unroll
      for (int ni = 0; ni < 8; ++ni) S[mi][ni] = (f32x4){0.f, 0.f, 0.f, 0.f};
    for (int kk = 0; kk < 8; ++kk) {
      __syncthreads();
#pragma unroll
      for (int rr = 0; rr < 4; ++rr) {
        int idx = rr * 256 + tid;
        int row = idx >> 3, ch = idx & 7;
        int dst = row * 64 + ((ch ^ (row & 7)) * 8);
        size_t asrc = (size_t)(cBase + row) * Dn + kk * 64 + ch * 8;
        *(s16x8*)&Ahi[dst] = *(const s16x8*)&mhi[asrc];
        *(s16x8*)&Alo[dst] = *(const s16x8*)&mlo[asrc];
        size_t bsrc = (size_t)(tt * 128 + row) * Dn + kk * 64 + ch * 8;
        *(s16x8*)&Bhi[dst] = *(const s16x8*)&khb[bsrc];
        *(s16x8*)&Blo[dst] = *(const s16x8*)&klb[bsrc];
      }
      __syncthreads();
#pragma unroll
      for (int ks2 = 0; ks2 < 2; ++ks2) {
        s16x8 ah[2], al[2];
#pragma unroll
        for (int mi = 0; mi < 2; ++mi) {
          int crow = w * 32 + mi * 16 + l15;
          int addr = crow * 64 + (((ks2 * 4 + g) ^ (crow & 7)) * 8);
          ah[mi] = *(const s16x8*)&Ahi[addr];
          al[mi] = *(const s16x8*)&Alo[addr];
        }
#pragma unroll
        for (int ni = 0; ni < 8; ++ni) {
          int trow = ni * 16 + l15;
          int addr = trow * 64 + (((ks2 * 4 + g) ^ (trow & 7)) * 8);
          s16x8 bh = *(const s16x8*)&Bhi[addr];
          s16x8 bl = *(const s16x8*)&Blo[addr];
#pragma unroll
          for (int mi = 0; mi < 2; ++mi) {
            S[mi][ni] = MFMA(ah[mi], bh, S[mi][ni]);
            S[mi][ni] = MFMA(ah[mi], bl, S[mi][ni]);
            S[mi][ni] = MFMA(al[mi], bh, S[mi][ni]);
          }
        }
      }
    }
#pragma unroll
    for (int ni = 0; ni < 8; ++ni) {
      float il = invl[b * Tn + tt * 128 + ni * 16 + l15];
#pragma unroll
      for (int mi = 0; mi < 2; ++mi)
#pragma unroll
        for (int r = 0; r < 4; ++r) uacc[mi][r] += __expf(S[mi][ni][r]) * il;
    }
  }
#pragma unroll
  for (int mi = 0; mi < 2; ++mi)
#pragma unroll
    for (int r = 0; r < 4; ++r) {
      float v = uacc[mi][r];
      v += __shfl_xor(v, 1);
      v += __shfl_xor(v, 2);
      v += __shfl_xor(v, 4);
      v += __shfl_xor(v, 8);
      if (l15 == 0)
        prio[(size_t)b * CAPn + cBase + w * 32 + mi * 16 + g * 4 + r] =
            comb[b] + 0.1f * v;
    }
}

// rank[b,c] = #{c' : prio[c'] > prio[c] or (== and c' < c)}  (jax top_k stable order)
__global__ __launch_bounds__(256) void k_rank(const float* __restrict__ prio,
                                              int* __restrict__ rank) {
  const int b = blockIdx.y;
  const int c = blockIdx.x * 256 + threadIdx.x;
  const float* p = prio + (size_t)b * CAPn;
  unsigned mb = __float_as_uint(p[c]);
  mb = (mb & 0x80000000u) ? ~mb : (mb | 0x80000000u);
  unsigned long long mykey =
      ((unsigned long long)mb << 32) | (unsigned)(0xFFFFFFFFu - c);
  __shared__ unsigned long long tile[2048];
  int cnt = 0;
  for (int base = 0; base < CAPn; base += 2048) {
    __syncthreads();
    for (int i = threadIdx.x; i < 2048; i += 256) {
      unsigned ub = __float_as_uint(p[base + i]);
      ub = (ub & 0x80000000u) ? ~ub : (ub | 0x80000000u);
      tile[i] = ((unsigned long long)ub << 32) | (unsigned)(0xFFFFFFFFu - (base + i));
    }
    __syncthreads();
#pragma unroll 8
    for (int i = 0; i < 2048; ++i) cnt += (tile[i] > mykey) ? 1 : 0;
  }
  rank[(size_t)b * CAPn + c] = cnt;
}

// new_mem (bf16) = 0.99*mem + 0.0025 * sum_b (rank_b[c] < K ? values[b, rank_b[c], :] : 0)
__global__ void k_newmem(const float* __restrict__ mem, const float* __restrict__ values,
                         const int* __restrict__ rank, ush* __restrict__ nm) {
  int gid = blockIdx.x * 256 + threadIdx.x;
  int c = gid >> 7;
  int q = (gid & 127) << 2;
  f32x4 m = *(const f32x4*)&mem[(size_t)c * Dn + q];
  f32x4 acc = {0.f, 0.f, 0.f, 0.f};
#pragma unroll
  for (int b = 0; b < Bn; ++b) {
    int r = rank[(size_t)b * CAPn + c];
    if (r < Kn) acc += *(const f32x4*)&values[((size_t)b * Tn + r) * Dn + q];
  }
  f32x4 res = m * MOM + acc * RATE_B;
  s16x4 o;
#pragma unroll
  for (int j = 0; j < 4; ++j) o[j] = (short)bfrn(res[j]);
  *(s16x4*)&nm[(size_t)c * Dn + q] = o;
}

// nmT[d][c] = nm[c][d]
__global__ void k_nmT(const ush* __restrict__ nm, ush* __restrict__ nmT) {
  __shared__ ush tile[64][65];
  int cBase = blockIdx.x * 64, dBase = blockIdx.y * 64;
  int tid = threadIdx.x;
#pragma unroll
  for (int rr = 0; rr < 2; ++rr) {
    int idx = rr * 256 + tid;
    int row = idx >> 3, ch = idx & 7;
    s16x8 v = *(const s16x8*)&nm[(size_t)(cBase + row) * Dn + dBase + ch * 8];
#pragma unroll
    for (int j = 0; j < 8; ++j) tile[row][ch * 8 + j] = (ush)v[j];
  }
  __syncthreads();
#pragma unroll
  for (int rr = 0; rr < 2; ++rr) {
    int idx = rr * 256 + tid;
    int drow = idx >> 3, ch = idx & 7;
    s16x8 v;
#pragma unroll
    for (int j = 0; j < 8; ++j) v[j] = (short)tile[ch * 8 + j][drow];
    *(s16x8*)&nmT[(size_t)(dBase + drow) * CAPn + cBase + ch * 8] = v;
  }
}

// Fused attn: per block 32 q-rows, half the CAP columns; S^T = mfma(M, Q),
// P packed in-lane to PV B-operand, O^T = mfma(Mt, P). outpart bf16.
__global__ __launch_bounds__(512, 2) void k_attnout(const ush* __restrict__ qbf,
                                                    const ush* __restrict__ nm,
                                                    const ush* __restrict__ nmT,
                                                    const float* __restrict__ invl,
                                                    ush* __restrict__ opart) {
  __shared__ ush Ms[128 * 64];    // [c 128][d 64]
  __shared__ ush Mts[128 * 128];  // [d 128][c 128]
  __shared__ ush Ps[4 * 2 * 64 * 8];
  const int tid = threadIdx.x;
  const int lane = tid & 63, w = tid >> 6;
  const int l15 = lane & 15, g = lane >> 4;
  const int qBase = blockIdx.x * 32;
  const int cy = blockIdx.y;

  s16x8 qfr[2][16];
  float il[2];
#pragma unroll
  for (int ni = 0; ni < 2; ++ni) {
    int qr = qBase + ni * 16 + l15;
    il[ni] = invl[qr];
#pragma unroll
    for (int ks = 0; ks < 16; ++ks)
      qfr[ni][ks] = *(const s16x8*)&qbf[(size_t)qr * Dn + ks * 32 + g * 8];
  }
  f32x4 O[4][2];
#pragma unroll
  for (int ds = 0; ds < 4; ++ds)
#pragma unroll
    for (int ni = 0; ni < 2; ++ni) O[ds][ni] = (f32x4){0.f, 0.f, 0.f, 0.f};

  for (int ct = 0; ct < 128; ++ct) {
    const int cBase = cy * 16384 + ct * 128;
    // ---- QK^T (transposed) ----
    f32x4 S[2];
    S[0] = (f32x4){0.f, 0.f, 0.f, 0.f};
    S[1] = (f32x4){0.f, 0.f, 0.f, 0.f};
#pragma unroll
    for (int kk = 0; kk < 8; ++kk) {
      __syncthreads();
#pragma unroll
      for (int rr = 0; rr < 2; ++rr) {
        int idx = rr * 512 + tid;
        int row = idx >> 3, ch = idx & 7;
        *(s16x8*)&Ms[row * 64 + ((ch ^ (row & 7)) * 8)] =
            *(const s16x8*)&nm[(size_t)(cBase + row) * Dn + kk * 64 + ch * 8];
      }
      __syncthreads();
#pragma unroll
      for (int ks2 = 0; ks2 < 2; ++ks2) {
        int crow = w * 16 + l15;
        s16x8 a = *(const s16x8*)&Ms[crow * 64 + (((ks2 * 4 + g) ^ (crow & 7)) * 8)];
        int ks = kk * 2 + ks2;
#pragma unroll
        for (int ni = 0; ni < 2; ++ni) S[ni] = MFMA(a, qfr[ni][ks], S[ni]);
      }
    }
    // ---- P = exp(S*SCALE)*il, packed in-lane into PV B-frag halves ----
#pragma unroll
    for (int ni = 0; ni < 2; ++ni) {
      s16x4 p;
#pragma unroll
      for (int r = 0; r < 4; ++r) p[r] = (short)bfrn(__expf(S[ni][r] * SCALE) * il[ni]);
      *(s16x4*)&Ps[(((w >> 1) * 2 + ni) * 64 + lane) * 8 + (w & 1) * 4] = p;
    }
    __syncthreads();
    s16x8 pb[4][2];
#pragma unroll
    for (int kc = 0; kc < 4; ++kc)
#pragma unroll
      for (int ni = 0; ni < 2; ++ni)
        pb[kc][ni] = *(const s16x8*)&Ps[((kc * 2 + ni) * 64 + lane) * 8];
    // ---- PV (transposed): O^T[d][q] += Mt[d][c] . P^T[c][q] ----
#pragma unroll
    for (int ds = 0; ds < 4; ++ds) {
      __syncthreads();
#pragma unroll
      for (int rr = 0; rr < 4; ++rr) {
        int idx = rr * 512 + tid;
        int row = idx >> 4, ch = idx & 15;
        *(s16x8*)&Mts[row * 128 + ((ch ^ (row & 7)) * 8)] =
            *(const s16x8*)&nmT[(size_t)(ds * 128 + row) * CAPn + cBase + ch * 8];
      }
      __syncthreads();
      int drow = w * 16 + l15;
#pragma unroll
      for (int kc = 0; kc < 4; ++kc) {
        int ch0 = (kc * 4 + (g >> 1)) ^ (drow & 7);
        int ch1 = (kc * 4 + (g >> 1) + 2) ^ (drow & 7);
        s16x4 a0 = *(const s16x4*)&Mts[drow * 128 + ch0 * 8 + (g & 1) * 4];
        s16x4 a1 = *(const s16x4*)&Mts[drow * 128 + ch1 * 8 + (g & 1) * 4];
        s16x8 a = __builtin_shufflevector(a0, a1, 0, 1, 2, 3, 4, 5, 6, 7);
#pragma unroll
        for (int ni = 0; ni < 2; ++ni) O[ds][ni] = MFMA(a, pb[kc][ni], O[ds][ni]);
      }
    }
  }
#pragma unroll
  for (int ds = 0; ds < 4; ++ds)
#pragma unroll
    for (int ni = 0; ni < 2; ++ni) {
      s16x4 o;
#pragma unroll
      for (int r = 0; r < 4; ++r) o[r] = (short)bfrn(O[ds][ni][r]);
      size_t row = (size_t)cy * ROWS + qBase + ni * 16 + l15;
      *(s16x4*)&opart[row * Dn + ds * 128 + w * 16 + g * 4] = o;
    }
}

__global__ void k_merge(const ush* __restrict__ opart, float* __restrict__ out) {
  size_t i = ((size_t)blockIdx.x * 256 + threadIdx.x) * 4;
  s16x4 a = *(const s16x4*)&opart[i];
  s16x4 b = *(const s16x4*)&opart[(size_t)ROWS * Dn + i];
  f32x4 o;
#pragma unroll
  for (int j = 0; j < 4; ++j) o[j] = bff((ush)a[j]) + bff((ush)b[j]);
  *(f32x4*)&out[i] = o;
}

extern "C" void kernel_launch(void* const* d_in, const int* in_sizes, int n_in,
                              void* d_out, int out_size, void* d_ws, size_t ws_size,
                              hipStream_t stream) {
  const float* keys = (const float*)d_in[0];
  const float* values = (const float*)d_in[1];
  const float* importance = (const float*)d_in[2];
  const float* query = (const float*)d_in[3];
  const float* mem = (const float*)d_in[4];
  char* wsb = (char*)d_ws;
  ush* nm    = (ush*)(wsb + OFF_NM);
  ush* nmT   = (ush*)(wsb + OFF_NMT);
  ush* mlo   = (ush*)(wsb + OFF_NM);   // alias (dead after k_usage)
  ush* mhi   = (ush*)(wsb + OFF_NMT);  // alias (dead after k_usage)
  ush* khi   = (ush*)(wsb + OFF_KHI);
  ush* klo   = (ush*)(wsb + OFF_KLO);
  ush* qbf   = (ush*)(wsb + OFF_QBF);
  ush* opart = (ush*)(wsb + OFF_OPART);
  float* zpart = (float*)(wsb + OFF_ZPART);
  float* invl1 = (float*)(wsb + OFF_INVL1);
  float* invl2 = (float*)(wsb + OFF_INVL2);
  float* prio  = (float*)(wsb + OFF_PRIO);
  int* rank    = (int*)(wsb + OFF_RANK);
  float* comb  = (float*)(wsb + OFF_COMB);
  float* out = (float*)d_out;

  k_combined<<<Bn, 256, 0, stream>>>(importance, comb);
  k_cvt_hilo<<<(ROWS * Dn / 4) / 256, 256, 0, stream>>>(keys, khi, klo);
  k_cvt_bf<<<(ROWS * Dn / 4) / 256, 256, 0, stream>>>(query, qbf);
  k_cvt_hilo<<<(CAPn * Dn / 4) / 256, 256, 0, stream>>>(mem, mhi, mlo);
  k_rowexp<false><<<CAPn / 64, 256, 0, stream>>>(mhi, khi, zpart);
  k_invl<<<ROWS / 256, 256, 0, stream>>>(zpart, invl1);
  k_usage<<<dim3(CAPn / 128, Bn), 256, 0, stream>>>(mhi, mlo, khi, klo, invl1, comb, prio);
  k_rank<<<dim3(CAPn / 256, Bn), 256, 0, stream>>>(prio, rank);
  k_newmem<<<(CAPn * Dn / 4) / 256, 256, 0, stream>>>(mem, values, rank, nm);
  k_nmT<<<dim3(CAPn / 64, Dn / 64), 256, 0, stream>>>(nm, nmT);
  k_rowexp<true><<<CAPn / 64, 256, 0, stream>>>(nm, qbf, zpart);
  k_invl<<<ROWS / 256, 256, 0, stream>>>(zpart, invl2);
  k_attnout<<<dim3(ROWS / 32, 2), 512, 0, stream>>>(qbf, nm, nmT, invl2, opart);
  k_merge<<<(ROWS * Dn / 4) / 256, 256, 0, stream>>>(opart, out);
}

// Round 3
// 1534.580 us; speedup vs baseline: 9.0043x; 1.9066x over previous
//
#include <hip/hip_runtime.h>

typedef float f32x4 __attribute__((ext_vector_type(4)));
typedef short s16x8 __attribute__((ext_vector_type(8)));
typedef short s16x4 __attribute__((ext_vector_type(4)));
typedef unsigned short ush;

constexpr int Bn = 4, Tn = 1024, Dn = 512, CAPn = 32768, Kn = 1024;
constexpr int ROWS = Bn * Tn; // 4096
constexpr float SCALE = 0.044194173824159216f; // 1/sqrt(512)
constexpr float MOM = 0.99f;
constexpr float RATE_B = 0.0025f; // 0.01 / B

// ---- workspace layout (byte offsets). Total 100.79e6 B (proven ws >= 102.0e6 B) ----
constexpr size_t OFF_NM    = 0;                      // bf16 [CAP][D] (alias: mem_lo early)
constexpr size_t OFF_NMT   = 33554432;               // bf16 [D][CAP] (alias: mem_hi early)
constexpr size_t OFF_OPART = 67108864;               // bf16 [8][ROWS][D] (late)  -- UNION with:
constexpr size_t OFF_KHI   = 67108864;               //   bf16 [ROWS][D] (early)
constexpr size_t OFF_KLO   = 71303168;               //   bf16 [ROWS][D] (early)
constexpr size_t OFF_ZPART = 75497472;               //   f32 [512][ROWS] (early)
constexpr size_t OFF_PRIO  = 83886080;               //   f32 [4][CAP] (early)
constexpr size_t OFF_RANK  = 84410368;               //   i32 [4][CAP] (early)
constexpr size_t OFF_COMB  = 84934656;               //   f32 [4] (early)
constexpr size_t OFF_ZP2   = 100663296;              // f32 [8][ROWS] (late)

#define MFMA(a, b, c) __builtin_amdgcn_mfma_f32_16x16x32_bf16((a), (b), (c), 0, 0, 0)

__device__ __forceinline__ ush bfrn(float x) {
  unsigned u = __float_as_uint(x);
  return (ush)((u + 0x7FFFu + ((u >> 16) & 1u)) >> 16);
}
__device__ __forceinline__ float bff(ush h) { return __uint_as_float(((unsigned)h) << 16); }

__device__ __forceinline__ void gl16(const ush* g, ush* l) {
  __builtin_amdgcn_global_load_lds(
      (const __attribute__((address_space(1))) void*)(uintptr_t)g,
      (__attribute__((address_space(3))) void*)(uintptr_t)l, 16, 0, 0);
}

// combined[b] = mean(importance[b,:,0])
__global__ void k_combined(const float* __restrict__ imp, float* __restrict__ comb) {
  __shared__ float red[256];
  int b = blockIdx.x;
  float s = 0.f;
  for (int t = threadIdx.x; t < Tn; t += 256) s += imp[(size_t)b * Tn + t];
  red[threadIdx.x] = s;
  __syncthreads();
  for (int off = 128; off > 0; off >>= 1) {
    if (threadIdx.x < (unsigned)off) red[threadIdx.x] += red[threadIdx.x + off];
    __syncthreads();
  }
  if (threadIdx.x == 0) comb[b] = red[0] * (1.0f / Tn);
}

// x -> hi (RTN bf16), lo (RTN bf16 of residual). 4 elems/thread.
__global__ void k_cvt_hilo(const float* __restrict__ x, ush* __restrict__ hi,
                           ush* __restrict__ lo) {
  size_t i = ((size_t)blockIdx.x * 256 + threadIdx.x) * 4;
  f32x4 v = *(const f32x4*)&x[i];
  s16x4 h, l;
#pragma unroll
  for (int j = 0; j < 4; ++j) {
    ush hh = bfrn(v[j]);
    h[j] = (short)hh;
    l[j] = (short)bfrn(v[j] - bff(hh));
  }
  *(s16x4*)&hi[i] = h;
  *(s16x4*)&lo[i] = l;
}

// Z partials: zpart[cb][t] = sum over this block's 64 c of exp(A[c,:].B[t,:])
template <bool SC>
__global__ __launch_bounds__(256, 2) void k_rowexp(const ush* __restrict__ Abf,
                                                   const ush* __restrict__ Bbf,
                                                   float* __restrict__ zpart) {
  __shared__ ush Bs[64 * 512];
  __shared__ float red[2][64];
  const int tid = threadIdx.x;
  const int lane = tid & 63, wid = tid >> 6;
  const int wc2 = wid >> 1, wt = wid & 1;
  const int l15 = lane & 15, g = lane >> 4;
  const int cb = blockIdx.x;
  const int cBase = cb * 64;

  s16x8 afr[2][16];
#pragma unroll
  for (int mi = 0; mi < 2; ++mi) {
    int c = cBase + wc2 * 32 + mi * 16 + l15;
#pragma unroll
    for (int ks = 0; ks < 16; ++ks)
      afr[mi][ks] = *(const s16x8*)&Abf[(size_t)c * Dn + ks * 32 + g * 8];
  }

  for (int tt = 0; tt < 64; ++tt) {
    const int tBase = tt * 64;
#pragma unroll
    for (int rr = 0; rr < 16; ++rr) {
      int idx = rr * 256 + tid;
      int row = idx >> 6, ch = idx & 63;
      s16x8 v = *(const s16x8*)&Bbf[(size_t)(tBase + row) * Dn + ch * 8];
      *(s16x8*)&Bs[row * 512 + ((ch ^ (row & 7)) * 8)] = v;
    }
    __syncthreads();
    f32x4 S[2][2];
#pragma unroll
    for (int mi = 0; mi < 2; ++mi)
#pragma unroll
      for (int ni = 0; ni < 2; ++ni) S[mi][ni] = (f32x4){0.f, 0.f, 0.f, 0.f};
#pragma unroll
    for (int ks = 0; ks < 16; ++ks) {
      s16x8 bfr[2];
#pragma unroll
      for (int ni = 0; ni < 2; ++ni) {
        int trow = wt * 32 + ni * 16 + l15;
        bfr[ni] = *(const s16x8*)&Bs[trow * 512 + (((ks * 4 + g) ^ (trow & 7)) * 8)];
      }
#pragma unroll
      for (int mi = 0; mi < 2; ++mi)
#pragma unroll
        for (int ni = 0; ni < 2; ++ni) S[mi][ni] = MFMA(afr[mi][ks], bfr[ni], S[mi][ni]);
    }
    float tacc[2] = {0.f, 0.f};
#pragma unroll
    for (int mi = 0; mi < 2; ++mi)
#pragma unroll
      for (int ni = 0; ni < 2; ++ni)
#pragma unroll
        for (int r = 0; r < 4; ++r)
          tacc[ni] += __expf(SC ? S[mi][ni][r] * SCALE : S[mi][ni][r]);
#pragma unroll
    for (int ni = 0; ni < 2; ++ni) {
      float v = tacc[ni];
      v += __shfl_xor(v, 16);
      v += __shfl_xor(v, 32);
      tacc[ni] = v;
    }
    if (g == 0) {
      red[wc2][wt * 32 + l15] = tacc[0];
      red[wc2][wt * 32 + 16 + l15] = tacc[1];
    }
    __syncthreads();
    if (tid < 64) zpart[(size_t)cb * ROWS + tBase + tid] = red[0][tid] + red[1][tid];
  }
}

__global__ void k_invl(const float* __restrict__ zpart, float* __restrict__ invl) {
  int t = blockIdx.x * 256 + threadIdx.x;
  float s = 0.f;
  for (int cb = 0; cb < 512; ++cb) s += zpart[(size_t)cb * ROWS + t];
  invl[t] = 1.0f / s;
}

// prio[b,c] = comb[b] + 0.1 * sum_t exp(scores[b,t,c]) * invl1[b,t]
__global__ __launch_bounds__(256, 2) void k_usage(const ush* __restrict__ mhi,
                                                  const ush* __restrict__ mlo,
                                                  const ush* __restrict__ khi,
                                                  const ush* __restrict__ klo,
                                                  const float* __restrict__ invl,
                                                  const float* __restrict__ comb,
                                                  float* __restrict__ prio) {
  __shared__ ush Ahi[128 * 64], Alo[128 * 64], Bhi[128 * 64], Blo[128 * 64];
  const int tid = threadIdx.x;
  const int lane = tid & 63, w = tid >> 6;
  const int l15 = lane & 15, g = lane >> 4;
  const int cBase = blockIdx.x * 128;
  const int b = blockIdx.y;
  const ush* khb = khi + (size_t)b * Tn * Dn;
  const ush* klb = klo + (size_t)b * Tn * Dn;

  float uacc[2][4] = {{0.f, 0.f, 0.f, 0.f}, {0.f, 0.f, 0.f, 0.f}};
  for (int tt = 0; tt < 8; ++tt) {
    f32x4 S[2][8];
#pragma unroll
    for (int mi = 0; mi < 2; ++mi)
#pragma unroll
      for (int ni = 0; ni < 8; ++ni) S[mi][ni] = (f32x4){0.f, 0.f, 0.f, 0.f};
    for (int kk = 0; kk < 8; ++kk) {
      __syncthreads();
#pragma unroll
      for (int rr = 0; rr < 4; ++rr) {
        int idx = rr * 256 + tid;
        int row = idx >> 3, ch = idx & 7;
        int dst = row * 64 + ((ch ^ (row & 7)) * 8);
        size_t asrc = (size_t)(cBase + row) * Dn + kk * 64 + ch * 8;
        *(s16x8*)&Ahi[dst] = *(const s16x8*)&mhi[asrc];
        *(s16x8*)&Alo[dst] = *(const s16x8*)&mlo[asrc];
        size_t bsrc = (size_t)(tt * 128 + row) * Dn + kk * 64 + ch * 8;
        *(s16x8*)&Bhi[dst] = *(const s16x8*)&khb[bsrc];
        *(s16x8*)&Blo[dst] = *(const s16x8*)&klb[bsrc];
      }
      __syncthreads();
#pragma unroll
      for (int ks2 = 0; ks2 < 2; ++ks2) {
        s16x8 ah[2], al[2];
#pragma unroll
        for (int mi = 0; mi < 2; ++mi) {
          int crow = w * 32 + mi * 16 + l15;
          int addr = crow * 64 + (((ks2 * 4 + g) ^ (crow & 7)) * 8);
          ah[mi] = *(const s16x8*)&Ahi[addr];
          al[mi] = *(const s16x8*)&Alo[addr];
        }
#pragma unroll
        for (int ni = 0; ni < 8; ++ni) {
          int trow = ni * 16 + l15;
          int addr = trow * 64 + (((ks2 * 4 + g) ^ (trow & 7)) * 8);
          s16x8 bh = *(const s16x8*)&Bhi[addr];
          s16x8 bl = *(const s16x8*)&Blo[addr];
#pragma unroll
          for (int mi = 0; mi < 2; ++mi) {
            S[mi][ni] = MFMA(ah[mi], bh, S[mi][ni]);
            S[mi][ni] = MFMA(ah[mi], bl, S[mi][ni]);
            S[mi][ni] = MFMA(al[mi], bh, S[mi][ni]);
          }
        }
      }
    }
#pragma unroll
    for (int ni = 0; ni < 8; ++ni) {
      float il = invl[b * Tn + tt * 128 + ni * 16 + l15];
#pragma unroll
      for (int mi = 0; mi < 2; ++mi)
#pragma unroll
        for (int r = 0; r < 4; ++r) uacc[mi][r] += __expf(S[mi][ni][r]) * il;
    }
  }
#pragma unroll
  for (int mi = 0; mi < 2; ++mi)
#pragma unroll
    for (int r = 0; r < 4; ++r) {
      float v = uacc[mi][r];
      v += __shfl_xor(v, 1);
      v += __shfl_xor(v, 2);
      v += __shfl_xor(v, 4);
      v += __shfl_xor(v, 8);
      if (l15 == 0)
        prio[(size_t)b * CAPn + cBase + w * 32 + mi * 16 + g * 4 + r] =
            comb[b] + 0.1f * v;
    }
}

// rank[b,c] = #{c' : prio[c'] > prio[c] or (== and c' < c)}
__global__ __launch_bounds__(256) void k_rank(const float* __restrict__ prio,
                                              int* __restrict__ rank) {
  const int b = blockIdx.y;
  const int c = blockIdx.x * 256 + threadIdx.x;
  const float* p = prio + (size_t)b * CAPn;
  unsigned mb = __float_as_uint(p[c]);
  mb = (mb & 0x80000000u) ? ~mb : (mb | 0x80000000u);
  unsigned long long mykey =
      ((unsigned long long)mb << 32) | (unsigned)(0xFFFFFFFFu - c);
  __shared__ unsigned long long tile[2048];
  int cnt = 0;
  for (int base = 0; base < CAPn; base += 2048) {
    __syncthreads();
    for (int i = threadIdx.x; i < 2048; i += 256) {
      unsigned ub = __float_as_uint(p[base + i]);
      ub = (ub & 0x80000000u) ? ~ub : (ub | 0x80000000u);
      tile[i] = ((unsigned long long)ub << 32) | (unsigned)(0xFFFFFFFFu - (base + i));
    }
    __syncthreads();
#pragma unroll 8
    for (int i = 0; i < 2048; ++i) cnt += (tile[i] > mykey) ? 1 : 0;
  }
  rank[(size_t)b * CAPn + c] = cnt;
}

// new_mem (bf16) = 0.99*mem + 0.0025 * sum_b (rank_b[c] < K ? values[b, rank_b[c], :] : 0)
__global__ void k_newmem(const float* __restrict__ mem, const float* __restrict__ values,
                         const int* __restrict__ rank, ush* __restrict__ nm) {
  int gid = blockIdx.x * 256 + threadIdx.x;
  int c = gid >> 7;
  int q = (gid & 127) << 2;
  f32x4 m = *(const f32x4*)&mem[(size_t)c * Dn + q];
  f32x4 acc = {0.f, 0.f, 0.f, 0.f};
#pragma unroll
  for (int b = 0; b < Bn; ++b) {
    int r = rank[(size_t)b * CAPn + c];
    if (r < Kn) acc += *(const f32x4*)&values[((size_t)b * Tn + r) * Dn + q];
  }
  f32x4 res = m * MOM + acc * RATE_B;
  s16x4 o;
#pragma unroll
  for (int j = 0; j < 4; ++j) o[j] = (short)bfrn(res[j]);
  *(s16x4*)&nm[(size_t)c * Dn + q] = o;
}

// nmT[d][c] = nm[c][d]
__global__ void k_nmT(const ush* __restrict__ nm, ush* __restrict__ nmT) {
  __shared__ ush tile[64][65];
  int cBase = blockIdx.x * 64, dBase = blockIdx.y * 64;
  int tid = threadIdx.x;
#pragma unroll
  for (int rr = 0; rr < 2; ++rr) {
    int idx = rr * 256 + tid;
    int row = idx >> 3, ch = idx & 7;
    s16x8 v = *(const s16x8*)&nm[(size_t)(cBase + row) * Dn + dBase + ch * 8];
#pragma unroll
    for (int j = 0; j < 8; ++j) tile[row][ch * 8 + j] = (ush)v[j];
  }
  __syncthreads();
#pragma unroll
  for (int rr = 0; rr < 2; ++rr) {
    int idx = rr * 256 + tid;
    int drow = idx >> 3, ch = idx & 7;
    s16x8 v;
#pragma unroll
    for (int j = 0; j < 8; ++j) v[j] = (short)tile[ch * 8 + j][drow];
    *(s16x8*)&nmT[(size_t)(dBase + drow) * CAPn + cBase + ch * 8] = v;
  }
}

// Fused attn: 128 q-rows x 4096 c per block (8 waves). Unnormalized:
// opart[cy] = sum_c exp(S*scale)_bf16 * M,  zp2[cy][q] = sum_c exp(S*scale).
// QK: S^T = mfma(M, Q); PV: O^T = mfma(Mt, P^T). m97-style dbuf pipeline.
// LDS (ush units): Ms[2][128][64] @0, Qs[2][128][64] @16384,
//                  Mt[2][128][64] @32768, Ps[128][128] @49152  (128 KB)
__global__ __launch_bounds__(512, 2) void k_attnout(
    const float* __restrict__ query, const ush* __restrict__ nm,
    const ush* __restrict__ nmT, ush* __restrict__ opart,
    float* __restrict__ zp2) {
  __shared__ ush lds[65536];
  __shared__ float zred[256];
  __shared__ float zacc[128];
  constexpr int LMS = 0, LQS = 16384, LMT = 32768, LPS = 49152;
  const int tid = threadIdx.x;
  const int lane = tid & 63, w = tid >> 6;
  const int l15 = lane & 15, g = lane >> 4;
  const int cw = w >> 2, qw = w & 3;  // c-half (QK) / d-half (PV); q-quarter
  const int qBase = blockIdx.x * 128;
  const int cy = blockIdx.y;
  const int r0 = tid >> 3, u0 = tid & 7;  // staging slot (round 0); round1: r0+64
  const int usw = (u0 ^ (r0 & 7)) << 3;   // pre-swizzled source element offset

  f32x4 O[4][4][2];
#pragma unroll
  for (int ds = 0; ds < 4; ++ds)
#pragma unroll
    for (int mi = 0; mi < 4; ++mi)
#pragma unroll
      for (int ni = 0; ni < 2; ++ni) O[ds][mi][ni] = (f32x4){0.f, 0.f, 0.f, 0.f};
  if (tid < 128) zacc[tid] = 0.f;

  for (int ct = 0; ct < 32; ++ct) {
    const int cBase = cy * 4096 + ct * 128;

    // ---- QK phase: S^T[128c][128q] over K=512, 8 chunks of 64, dbuf ----
    f32x4 S[4][2];
#pragma unroll
    for (int mi = 0; mi < 4; ++mi)
#pragma unroll
      for (int ni = 0; ni < 2; ++ni) S[mi][ni] = (f32x4){0.f, 0.f, 0.f, 0.f};

    auto stage_m = [&](int buf, int kk) {
      const ush* src = nm + (size_t)cBase * Dn + kk * 64;
      gl16(&src[(size_t)r0 * Dn + usw], &lds[LMS + buf * 8192 + w * 512]);
      gl16(&src[(size_t)(r0 + 64) * Dn + usw], &lds[LMS + buf * 8192 + 4096 + w * 512]);
    };
    auto load_q = [&](int kk, f32x4 qv[4]) {
      const float* src = query + (size_t)qBase * Dn + kk * 64;
      const float* p0 = &src[(size_t)r0 * Dn + usw];
      const float* p1 = &src[(size_t)(r0 + 64) * Dn + usw];
      qv[0] = *(const f32x4*)p0;
      qv[1] = *(const f32x4*)(p0 + 4);
      qv[2] = *(const f32x4*)p1;
      qv[3] = *(const f32x4*)(p1 + 4);
    };
    auto store_q = [&](int buf, const f32x4 qv[4]) {
      s16x8 h0, h1;
#pragma unroll
      for (int j = 0; j < 4; ++j) {
        h0[j] = (short)bfrn(qv[0][j]);
        h0[4 + j] = (short)bfrn(qv[1][j]);
        h1[j] = (short)bfrn(qv[2][j]);
        h1[4 + j] = (short)bfrn(qv[3][j]);
      }
      *(s16x8*)&lds[LQS + buf * 8192 + tid * 8] = h0;
      *(s16x8*)&lds[LQS + buf * 8192 + 4096 + tid * 8] = h1;
    };

    {  // prologue: stage chunk 0 into buf 0
      f32x4 qv[4];
      load_q(0, qv);
      stage_m(0, 0);
      store_q(0, qv);
    }
    __syncthreads();
    int qb = 0;
    for (int kk = 0; kk < 8; ++kk) {
      f32x4 qv[4];
      if (kk < 7) {
        load_q(kk + 1, qv);
        stage_m(qb ^ 1, kk + 1);
      }
#pragma unroll
      for (int ks2 = 0; ks2 < 2; ++ks2) {
        s16x8 am[4], bq[2];
#pragma unroll
        for (int mi = 0; mi < 4; ++mi) {
          int row = cw * 64 + mi * 16 + l15;
          am[mi] = *(const s16x8*)&lds[LMS + qb * 8192 + row * 64 +
                                       (((ks2 * 4 + g) ^ (row & 7)) << 3)];
        }
#pragma unroll
        for (int ni = 0; ni < 2; ++ni) {
          int row = qw * 32 + ni * 16 + l15;
          bq[ni] = *(const s16x8*)&lds[LQS + qb * 8192 + row * 64 +
                                       (((ks2 * 4 + g) ^ (row & 7)) << 3)];
        }
#pragma unroll
        for (int mi = 0; mi < 4; ++mi)
#pragma unroll
          for (int ni = 0; ni < 2; ++ni) S[mi][ni] = MFMA(am[mi], bq[ni], S[mi][ni]);
      }
      if (kk < 7) store_q(qb ^ 1, qv);
      __syncthreads();
      qb ^= 1;
    }

    // ---- P = exp(S*SCALE) (unnormalized), write Ps + z-partials ----
    auto stage_mt = [&](int buf, int u) {
      int ds = u >> 1, hh = u & 1;
      const ush* src = nmT + (size_t)(ds * 128) * CAPn + cBase + hh * 64;
      gl16(&src[(size_t)r0 * CAPn + usw], &lds[LMT + buf * 8192 + w * 512]);
      gl16(&src[(size_t)(r0 + 64) * CAPn + usw], &lds[LMT + buf * 8192 + 4096 + w * 512]);
    };

    float zl[2] = {0.f, 0.f};
#pragma unroll
    for (int ni = 0; ni < 2; ++ni) {
      int q = qw * 32 + ni * 16 + l15;
#pragma unroll
      for (int mi = 0; mi < 4; ++mi) {
        s16x4 p;
#pragma unroll
        for (int r = 0; r < 4; ++r) {
          float e = __expf(S[mi][ni][r] * SCALE);
          zl[ni] += e;
          p[r] = (short)bfrn(e);
        }
        int u16 = (cw * 8 + mi * 2 + (g >> 1)) ^ (q & 15);
        *(s16x4*)&lds[LPS + q * 128 + u16 * 8 + (g & 1) * 4] = p;
      }
      float v = zl[ni];
      v += __shfl_xor(v, 16);
      v += __shfl_xor(v, 32);
      if (g == 0) zred[((cw * 4 + qw) * 2 + ni) * 16 + l15] = v;
    }
    stage_mt(0, 0);
    __syncthreads();
    if (tid < 128) {
      int qw2 = tid >> 5, ni2 = (tid >> 4) & 1, lq = tid & 15;
      zacc[tid] += zred[((qw2)*2 + ni2) * 16 + lq] + zred[((4 + qw2) * 2 + ni2) * 16 + lq];
    }

    // ---- PV phase: O^T[512d][128q] += Mt . P^T, 8 units (4 dsub x 2 c-half) ----
    int mb = 0;
#pragma unroll
    for (int u = 0; u < 8; ++u) {
      const int ds = u >> 1, hh = u & 1;
      if (u < 7) stage_mt(mb ^ 1, u + 1);
#pragma unroll
      for (int kc = 0; kc < 2; ++kc) {
        s16x8 am[4], pb[2];
#pragma unroll
        for (int mi = 0; mi < 4; ++mi) {
          int row = cw * 64 + mi * 16 + l15;  // d-row within dsub
          am[mi] = *(const s16x8*)&lds[LMT + mb * 8192 + row * 64 +
                                       (((kc * 4 + g) ^ (row & 7)) << 3)];
        }
#pragma unroll
        for (int ni = 0; ni < 2; ++ni) {
          int q = qw * 32 + ni * 16 + l15;
          int u16 = (hh * 8 + kc * 4 + g) ^ (q & 15);
          pb[ni] = *(const s16x8*)&lds[LPS + q * 128 + u16 * 8];
        }
#pragma unroll
        for (int mi = 0; mi < 4; ++mi)
#pragma unroll
          for (int ni = 0; ni < 2; ++ni)
            O[ds][mi][ni] = MFMA(am[mi], pb[ni], O[ds][mi][ni]);
      }
      __syncthreads();
      mb ^= 1;
    }
  }

  // ---- epilogue: z + O stores (O transposed through LDS for coalescing) ----
  if (tid < 128) zp2[(size_t)cy * ROWS + qBase + tid] = zacc[tid];
#pragma unroll
  for (int ds = 0; ds < 4; ++ds) {
    __syncthreads();
#pragma unroll
    for (int ni = 0; ni < 2; ++ni) {
      int q = qw * 32 + ni * 16 + l15;
#pragma unroll
      for (int mi = 0; mi < 4; ++mi) {
        s16x4 ov;
#pragma unroll
        for (int r = 0; r < 4; ++r) ov[r] = (short)bfrn(O[ds][mi][ni][r]);
        int u16 = (cw * 8 + mi * 2 + (g >> 1)) ^ (q & 15);
        *(s16x4*)&lds[LPS + q * 128 + u16 * 8 + (g & 1) * 4] = ov;
      }
    }
    __syncthreads();
#pragma unroll
    for (int i = 0; i < 4; ++i) {
      int slot = i * 512 + tid;
      int q = slot >> 4, u16 = slot & 15;
      s16x8 v = *(const s16x8*)&lds[LPS + q * 128 + ((u16 ^ (q & 15)) << 3)];
      *(s16x8*)&opart[((size_t)cy * ROWS + qBase + q) * Dn + ds * 128 + u16 * 8] = v;
    }
  }
}

// out = (sum_cy opart[cy]) / (sum_cy zp2[cy]) per row
__global__ void k_merge(const ush* __restrict__ opart, const float* __restrict__ zp2,
                        float* __restrict__ out) {
  size_t i = ((size_t)blockIdx.x * 256 + threadIdx.x) * 4;
  int row = (int)(i >> 9);
  float z = 0.f;
#pragma unroll
  for (int cyy = 0; cyy < 8; ++cyy) z += zp2[(size_t)cyy * ROWS + row];
  float inv = 1.0f / z;
  f32x4 acc = {0.f, 0.f, 0.f, 0.f};
#pragma unroll
  for (int cyy = 0; cyy < 8; ++cyy) {
    s16x4 a = *(const s16x4*)&opart[(size_t)cyy * ROWS * Dn + i];
#pragma unroll
    for (int j = 0; j < 4; ++j) acc[j] += bff((ush)a[j]);
  }
#pragma unroll
  for (int j = 0; j < 4; ++j) acc[j] *= inv;
  *(f32x4*)&out[i] = acc;
}

extern "C" void kernel_launch(void* const* d_in, const int* in_sizes, int n_in,
                              void* d_out, int out_size, void* d_ws, size_t ws_size,
                              hipStream_t stream) {
  const float* keys = (const float*)d_in[0];
  const float* values = (const float*)d_in[1];
  const float* importance = (const float*)d_in[2];
  const float* query = (const float*)d_in[3];
  const float* mem = (const float*)d_in[4];
  char* wsb = (char*)d_ws;
  ush* nm    = (ush*)(wsb + OFF_NM);
  ush* nmT   = (ush*)(wsb + OFF_NMT);
  ush* mlo   = (ush*)(wsb + OFF_NM);   // alias (dead after k_usage)
  ush* mhi   = (ush*)(wsb + OFF_NMT);  // alias (dead after k_usage)
  ush* khi   = (ush*)(wsb + OFF_KHI);
  ush* klo   = (ush*)(wsb + OFF_KLO);
  ush* opart = (ush*)(wsb + OFF_OPART);
  float* zpart = (float*)(wsb + OFF_ZPART);
  float* prio  = (float*)(wsb + OFF_PRIO);
  int* rank    = (int*)(wsb + OFF_RANK);
  float* comb  = (float*)(wsb + OFF_COMB);
  float* zp2   = (float*)(wsb + OFF_ZP2);
  // invl1 shares the comb cacheline region? No: place after comb (early region)
  float* invl1 = (float*)(wsb + OFF_COMB + 64);
  float* out = (float*)d_out;

  k_combined<<<Bn, 256, 0, stream>>>(importance, comb);
  k_cvt_hilo<<<(ROWS * Dn / 4) / 256, 256, 0, stream>>>(keys, khi, klo);
  k_cvt_hilo<<<(CAPn * Dn / 4) / 256, 256, 0, stream>>>(mem, mhi, mlo);
  k_rowexp<false><<<CAPn / 64, 256, 0, stream>>>(mhi, khi, zpart);
  k_invl<<<ROWS / 256, 256, 0, stream>>>(zpart, invl1);
  k_usage<<<dim3(CAPn / 128, Bn), 256, 0, stream>>>(mhi, mlo, khi, klo, invl1, comb, prio);
  k_rank<<<dim3(CAPn / 256, Bn), 256, 0, stream>>>(prio, rank);
  k_newmem<<<(CAPn * Dn / 4) / 256, 256, 0, stream>>>(mem, values, rank, nm);
  k_nmT<<<dim3(CAPn / 64, Dn / 64), 256, 0, stream>>>(nm, nmT);
  k_attnout<<<dim3(ROWS / 128, 8), 512, 0, stream>>>(query, nm, nmT, opart, zp2);
  k_merge<<<(ROWS * Dn / 4) / 256, 256, 0, stream>>>(opart, zp2, out);
}

// Round 4
// 1233.028 us; speedup vs baseline: 11.2064x; 1.2446x over previous
//
#include <hip/hip_runtime.h>

typedef float f32x4 __attribute__((ext_vector_type(4)));
typedef short s16x8 __attribute__((ext_vector_type(8)));
typedef short s16x4 __attribute__((ext_vector_type(4)));
typedef unsigned short ush;

constexpr int Bn = 4, Tn = 1024, Dn = 512, CAPn = 32768, Kn = 1024;
constexpr int ROWS = Bn * Tn; // 4096
constexpr float SCALE = 0.044194173824159216f; // 1/sqrt(512)
constexpr float MOM = 0.99f;
constexpr float RATE_B = 0.0025f; // 0.01 / B

// ---- workspace layout (byte offsets). Total 100.79e6 B (proven ws >= 102.0e6 B) ----
constexpr size_t OFF_NM    = 0;                      // bf16 [CAP][D] (alias: mem_lo early)
constexpr size_t OFF_NMT   = 33554432;               // bf16 [D][CAP] (alias: mem_hi early)
constexpr size_t OFF_OPART = 67108864;               // bf16 [8][ROWS][D] (late)  -- UNION with:
constexpr size_t OFF_KHI   = 67108864;               //   bf16 [ROWS][D] (early)
constexpr size_t OFF_KLO   = 71303168;               //   bf16 [ROWS][D] (early)
constexpr size_t OFF_ZPART = 75497472;               //   f32 [512][ROWS] (early)
constexpr size_t OFF_PRIO  = 83886080;               //   f32 [4][CAP] (early)
constexpr size_t OFF_RANK  = 84410368;               //   i32 [4][CAP] (early)
constexpr size_t OFF_COMB  = 84934656;               //   f32 [4] (early)
constexpr size_t OFF_ZP2   = 100663296;              // f32 [8][ROWS] (late)

#define MFMA(a, b, c) __builtin_amdgcn_mfma_f32_16x16x32_bf16((a), (b), (c), 0, 0, 0)

__device__ __forceinline__ ush bfrn(float x) {
  unsigned u = __float_as_uint(x);
  return (ush)((u + 0x7FFFu + ((u >> 16) & 1u)) >> 16);
}
__device__ __forceinline__ float bff(ush h) { return __uint_as_float(((unsigned)h) << 16); }

__device__ __forceinline__ void gl16(const ush* g, ush* l) {
  __builtin_amdgcn_global_load_lds(
      (const __attribute__((address_space(1))) void*)(uintptr_t)g,
      (__attribute__((address_space(3))) void*)(uintptr_t)l, 16, 0, 0);
}

// combined[b] = mean(importance[b,:,0])
__global__ void k_combined(const float* __restrict__ imp, float* __restrict__ comb) {
  __shared__ float red[256];
  int b = blockIdx.x;
  float s = 0.f;
  for (int t = threadIdx.x; t < Tn; t += 256) s += imp[(size_t)b * Tn + t];
  red[threadIdx.x] = s;
  __syncthreads();
  for (int off = 128; off > 0; off >>= 1) {
    if (threadIdx.x < (unsigned)off) red[threadIdx.x] += red[threadIdx.x + off];
    __syncthreads();
  }
  if (threadIdx.x == 0) comb[b] = red[0] * (1.0f / Tn);
}

// x -> hi (RTN bf16), lo (RTN bf16 of residual). 4 elems/thread.
__global__ void k_cvt_hilo(const float* __restrict__ x, ush* __restrict__ hi,
                           ush* __restrict__ lo) {
  size_t i = ((size_t)blockIdx.x * 256 + threadIdx.x) * 4;
  f32x4 v = *(const f32x4*)&x[i];
  s16x4 h, l;
#pragma unroll
  for (int j = 0; j < 4; ++j) {
    ush hh = bfrn(v[j]);
    h[j] = (short)hh;
    l[j] = (short)bfrn(v[j] - bff(hh));
  }
  *(s16x4*)&hi[i] = h;
  *(s16x4*)&lo[i] = l;
}

// Z partials: zpart[cb][t] = sum over this block's 64 c of exp(A[c,:].B[t,:])
template <bool SC>
__global__ __launch_bounds__(256, 2) void k_rowexp(const ush* __restrict__ Abf,
                                                   const ush* __restrict__ Bbf,
                                                   float* __restrict__ zpart) {
  __shared__ ush Bs[64 * 512];
  __shared__ float red[2][64];
  const int tid = threadIdx.x;
  const int lane = tid & 63, wid = tid >> 6;
  const int wc2 = wid >> 1, wt = wid & 1;
  const int l15 = lane & 15, g = lane >> 4;
  const int cb = blockIdx.x;
  const int cBase = cb * 64;

  s16x8 afr[2][16];
#pragma unroll
  for (int mi = 0; mi < 2; ++mi) {
    int c = cBase + wc2 * 32 + mi * 16 + l15;
#pragma unroll
    for (int ks = 0; ks < 16; ++ks)
      afr[mi][ks] = *(const s16x8*)&Abf[(size_t)c * Dn + ks * 32 + g * 8];
  }

  for (int tt = 0; tt < 64; ++tt) {
    const int tBase = tt * 64;
#pragma unroll
    for (int rr = 0; rr < 16; ++rr) {
      int idx = rr * 256 + tid;
      int row = idx >> 6, ch = idx & 63;
      s16x8 v = *(const s16x8*)&Bbf[(size_t)(tBase + row) * Dn + ch * 8];
      *(s16x8*)&Bs[row * 512 + ((ch ^ (row & 7)) * 8)] = v;
    }
    __syncthreads();
    f32x4 S[2][2];
#pragma unroll
    for (int mi = 0; mi < 2; ++mi)
#pragma unroll
      for (int ni = 0; ni < 2; ++ni) S[mi][ni] = (f32x4){0.f, 0.f, 0.f, 0.f};
#pragma unroll
    for (int ks = 0; ks < 16; ++ks) {
      s16x8 bfr[2];
#pragma unroll
      for (int ni = 0; ni < 2; ++ni) {
        int trow = wt * 32 + ni * 16 + l15;
        bfr[ni] = *(const s16x8*)&Bs[trow * 512 + (((ks * 4 + g) ^ (trow & 7)) * 8)];
      }
#pragma unroll
      for (int mi = 0; mi < 2; ++mi)
#pragma unroll
        for (int ni = 0; ni < 2; ++ni) S[mi][ni] = MFMA(afr[mi][ks], bfr[ni], S[mi][ni]);
    }
    float tacc[2] = {0.f, 0.f};
#pragma unroll
    for (int mi = 0; mi < 2; ++mi)
#pragma unroll
      for (int ni = 0; ni < 2; ++ni)
#pragma unroll
        for (int r = 0; r < 4; ++r)
          tacc[ni] += __expf(SC ? S[mi][ni][r] * SCALE : S[mi][ni][r]);
#pragma unroll
    for (int ni = 0; ni < 2; ++ni) {
      float v = tacc[ni];
      v += __shfl_xor(v, 16);
      v += __shfl_xor(v, 32);
      tacc[ni] = v;
    }
    if (g == 0) {
      red[wc2][wt * 32 + l15] = tacc[0];
      red[wc2][wt * 32 + 16 + l15] = tacc[1];
    }
    __syncthreads();
    if (tid < 64) zpart[(size_t)cb * ROWS + tBase + tid] = red[0][tid] + red[1][tid];
  }
}

__global__ void k_invl(const float* __restrict__ zpart, float* __restrict__ invl) {
  int t = blockIdx.x * 256 + threadIdx.x;
  float s = 0.f;
  for (int cb = 0; cb < 512; ++cb) s += zpart[(size_t)cb * ROWS + t];
  invl[t] = 1.0f / s;
}

// prio[b,c] = comb[b] + 0.1 * sum_t exp(scores[b,t,c]) * invl1[b,t]
__global__ __launch_bounds__(256, 2) void k_usage(const ush* __restrict__ mhi,
                                                  const ush* __restrict__ mlo,
                                                  const ush* __restrict__ khi,
                                                  const ush* __restrict__ klo,
                                                  const float* __restrict__ invl,
                                                  const float* __restrict__ comb,
                                                  float* __restrict__ prio) {
  __shared__ ush Ahi[128 * 64], Alo[128 * 64], Bhi[128 * 64], Blo[128 * 64];
  const int tid = threadIdx.x;
  const int lane = tid & 63, w = tid >> 6;
  const int l15 = lane & 15, g = lane >> 4;
  const int cBase = blockIdx.x * 128;
  const int b = blockIdx.y;
  const ush* khb = khi + (size_t)b * Tn * Dn;
  const ush* klb = klo + (size_t)b * Tn * Dn;

  float uacc[2][4] = {{0.f, 0.f, 0.f, 0.f}, {0.f, 0.f, 0.f, 0.f}};
  for (int tt = 0; tt < 8; ++tt) {
    f32x4 S[2][8];
#pragma unroll
    for (int mi = 0; mi < 2; ++mi)
#pragma unroll
      for (int ni = 0; ni < 8; ++ni) S[mi][ni] = (f32x4){0.f, 0.f, 0.f, 0.f};
    for (int kk = 0; kk < 8; ++kk) {
      __syncthreads();
#pragma unroll
      for (int rr = 0; rr < 4; ++rr) {
        int idx = rr * 256 + tid;
        int row = idx >> 3, ch = idx & 7;
        int dst = row * 64 + ((ch ^ (row & 7)) * 8);
        size_t asrc = (size_t)(cBase + row) * Dn + kk * 64 + ch * 8;
        *(s16x8*)&Ahi[dst] = *(const s16x8*)&mhi[asrc];
        *(s16x8*)&Alo[dst] = *(const s16x8*)&mlo[asrc];
        size_t bsrc = (size_t)(tt * 128 + row) * Dn + kk * 64 + ch * 8;
        *(s16x8*)&Bhi[dst] = *(const s16x8*)&khb[bsrc];
        *(s16x8*)&Blo[dst] = *(const s16x8*)&klb[bsrc];
      }
      __syncthreads();
#pragma unroll
      for (int ks2 = 0; ks2 < 2; ++ks2) {
        s16x8 ah[2], al[2];
#pragma unroll
        for (int mi = 0; mi < 2; ++mi) {
          int crow = w * 32 + mi * 16 + l15;
          int addr = crow * 64 + (((ks2 * 4 + g) ^ (crow & 7)) * 8);
          ah[mi] = *(const s16x8*)&Ahi[addr];
          al[mi] = *(const s16x8*)&Alo[addr];
        }
#pragma unroll
        for (int ni = 0; ni < 8; ++ni) {
          int trow = ni * 16 + l15;
          int addr = trow * 64 + (((ks2 * 4 + g) ^ (trow & 7)) * 8);
          s16x8 bh = *(const s16x8*)&Bhi[addr];
          s16x8 bl = *(const s16x8*)&Blo[addr];
#pragma unroll
          for (int mi = 0; mi < 2; ++mi) {
            S[mi][ni] = MFMA(ah[mi], bh, S[mi][ni]);
            S[mi][ni] = MFMA(ah[mi], bl, S[mi][ni]);
            S[mi][ni] = MFMA(al[mi], bh, S[mi][ni]);
          }
        }
      }
    }
#pragma unroll
    for (int ni = 0; ni < 8; ++ni) {
      float il = invl[b * Tn + tt * 128 + ni * 16 + l15];
#pragma unroll
      for (int mi = 0; mi < 2; ++mi)
#pragma unroll
        for (int r = 0; r < 4; ++r) uacc[mi][r] += __expf(S[mi][ni][r]) * il;
    }
  }
#pragma unroll
  for (int mi = 0; mi < 2; ++mi)
#pragma unroll
    for (int r = 0; r < 4; ++r) {
      float v = uacc[mi][r];
      v += __shfl_xor(v, 1);
      v += __shfl_xor(v, 2);
      v += __shfl_xor(v, 4);
      v += __shfl_xor(v, 8);
      if (l15 == 0)
        prio[(size_t)b * CAPn + cBase + w * 32 + mi * 16 + g * 4 + r] =
            comb[b] + 0.1f * v;
    }
}

// rank init: unselected slots get Kn (k_newmem tests r < Kn)
__global__ void k_rankinit(int* __restrict__ rank) {
  rank[blockIdx.x * 256 + threadIdx.x] = Kn;
}

// Per-batch exact top-K selection + stable rank, replacing O(CAP^2) k_rank.
// Keys are distinct u64 (flipped prio bits | ~index); MSB-first 8-bit radix
// select finds the exact 1024th-largest key T; the 1024 keys >= T get ranks
// by count-of-greater within the selected set. Identical results to jax
// top_k stable ordering.
__global__ __launch_bounds__(1024) void k_select(const float* __restrict__ prio,
                                                 int* __restrict__ rank) {
  const int b = blockIdx.x;
  const float* p = prio + (size_t)b * CAPn;
  __shared__ int hist[256];
  __shared__ unsigned long long s_pref;
  __shared__ int s_krem;
  __shared__ int s_cnt;
  __shared__ unsigned long long selk[Kn];
  const int tid = threadIdx.x;
  if (tid == 0) { s_pref = 0ull; s_krem = Kn; s_cnt = 0; }

#define KEYOF(c, kk)                                                         \
  {                                                                          \
    unsigned mb_ = __float_as_uint(p[(c)]);                                  \
    mb_ = (mb_ & 0x80000000u) ? ~mb_ : (mb_ | 0x80000000u);                  \
    (kk) = ((unsigned long long)mb_ << 32) | (unsigned)(0xFFFFFFFFu - (c));  \
  }

  __syncthreads();
  for (int pos = 56; pos >= 0; pos -= 8) {
    if (tid < 256) hist[tid] = 0;
    __syncthreads();
    unsigned long long pref = s_pref;
    unsigned long long maskhi = (pos == 56) ? 0ull : (~0ull << (pos + 8));
    for (int c = tid; c < CAPn; c += 1024) {
      unsigned long long k;
      KEYOF(c, k);
      if ((k & maskhi) == pref) atomicAdd(&hist[(int)((k >> pos) & 255)], 1);
    }
    __syncthreads();
    if (tid == 0) {
      int krem = s_krem;
      int d = 255;
      for (;; --d) {
        int h = hist[d];
        if (krem <= h || d == 0) break;
        krem -= h;
      }
      s_pref = pref | ((unsigned long long)d << pos);
      s_krem = krem;
    }
    __syncthreads();
  }
  unsigned long long T = s_pref;  // exact Kn-th largest key
  for (int c = tid; c < CAPn; c += 1024) {
    unsigned long long k;
    KEYOF(c, k);
    if (k >= T) {
      int idx = atomicAdd(&s_cnt, 1);
      selk[idx] = k;
    }
  }
  __syncthreads();
  unsigned long long mine = selk[tid];
  int r = 0;
  for (int j = 0; j < Kn; ++j) r += (selk[j] > mine) ? 1 : 0;
  int c = (int)(0xFFFFFFFFu - (unsigned)(mine & 0xFFFFFFFFull));
  rank[(size_t)b * CAPn + c] = r;
#undef KEYOF
}

// new_mem (bf16) = 0.99*mem + 0.0025 * sum_b (rank_b[c] < K ? values[b, rank_b[c], :] : 0)
__global__ void k_newmem(const float* __restrict__ mem, const float* __restrict__ values,
                         const int* __restrict__ rank, ush* __restrict__ nm) {
  int gid = blockIdx.x * 256 + threadIdx.x;
  int c = gid >> 7;
  int q = (gid & 127) << 2;
  f32x4 m = *(const f32x4*)&mem[(size_t)c * Dn + q];
  f32x4 acc = {0.f, 0.f, 0.f, 0.f};
#pragma unroll
  for (int b = 0; b < Bn; ++b) {
    int r = rank[(size_t)b * CAPn + c];
    if (r < Kn) acc += *(const f32x4*)&values[((size_t)b * Tn + r) * Dn + q];
  }
  f32x4 res = m * MOM + acc * RATE_B;
  s16x4 o;
#pragma unroll
  for (int j = 0; j < 4; ++j) o[j] = (short)bfrn(res[j]);
  *(s16x4*)&nm[(size_t)c * Dn + q] = o;
}

// nmT[d][c] = nm[c][d]
__global__ void k_nmT(const ush* __restrict__ nm, ush* __restrict__ nmT) {
  __shared__ ush tile[64][65];
  int cBase = blockIdx.x * 64, dBase = blockIdx.y * 64;
  int tid = threadIdx.x;
#pragma unroll
  for (int rr = 0; rr < 2; ++rr) {
    int idx = rr * 256 + tid;
    int row = idx >> 3, ch = idx & 7;
    s16x8 v = *(const s16x8*)&nm[(size_t)(cBase + row) * Dn + dBase + ch * 8];
#pragma unroll
    for (int j = 0; j < 8; ++j) tile[row][ch * 8 + j] = (ush)v[j];
  }
  __syncthreads();
#pragma unroll
  for (int rr = 0; rr < 2; ++rr) {
    int idx = rr * 256 + tid;
    int drow = idx >> 3, ch = idx & 7;
    s16x8 v;
#pragma unroll
    for (int j = 0; j < 8; ++j) v[j] = (short)tile[ch * 8 + j][drow];
    *(s16x8*)&nmT[(size_t)(dBase + drow) * CAPn + cBase + ch * 8] = v;
  }
}

// Fused attn: 128 q-rows x 4096 c per block (8 waves). Unnormalized:
// opart[cy] = sum_c exp(S*scale)_bf16 * M,  zp2[cy][q] = sum_c exp(S*scale).
__global__ __launch_bounds__(512, 2) void k_attnout(
    const float* __restrict__ query, const ush* __restrict__ nm,
    const ush* __restrict__ nmT, ush* __restrict__ opart,
    float* __restrict__ zp2) {
  __shared__ ush lds[65536];
  __shared__ float zred[256];
  __shared__ float zacc[128];
  constexpr int LMS = 0, LQS = 16384, LMT = 32768, LPS = 49152;
  const int tid = threadIdx.x;
  const int lane = tid & 63, w = tid >> 6;
  const int l15 = lane & 15, g = lane >> 4;
  const int cw = w >> 2, qw = w & 3;
  const int qBase = blockIdx.x * 128;
  const int cy = blockIdx.y;
  const int r0 = tid >> 3, u0 = tid & 7;
  const int usw = (u0 ^ (r0 & 7)) << 3;

  f32x4 O[4][4][2];
#pragma unroll
  for (int ds = 0; ds < 4; ++ds)
#pragma unroll
    for (int mi = 0; mi < 4; ++mi)
#pragma unroll
      for (int ni = 0; ni < 2; ++ni) O[ds][mi][ni] = (f32x4){0.f, 0.f, 0.f, 0.f};
  if (tid < 128) zacc[tid] = 0.f;

  for (int ct = 0; ct < 32; ++ct) {
    const int cBase = cy * 4096 + ct * 128;

    f32x4 S[4][2];
#pragma unroll
    for (int mi = 0; mi < 4; ++mi)
#pragma unroll
      for (int ni = 0; ni < 2; ++ni) S[mi][ni] = (f32x4){0.f, 0.f, 0.f, 0.f};

    auto stage_m = [&](int buf, int kk) {
      const ush* src = nm + (size_t)cBase * Dn + kk * 64;
      gl16(&src[(size_t)r0 * Dn + usw], &lds[LMS + buf * 8192 + w * 512]);
      gl16(&src[(size_t)(r0 + 64) * Dn + usw], &lds[LMS + buf * 8192 + 4096 + w * 512]);
    };
    auto load_q = [&](int kk, f32x4 qv[4]) {
      const float* src = query + (size_t)qBase * Dn + kk * 64;
      const float* p0 = &src[(size_t)r0 * Dn + usw];
      const float* p1 = &src[(size_t)(r0 + 64) * Dn + usw];
      qv[0] = *(const f32x4*)p0;
      qv[1] = *(const f32x4*)(p0 + 4);
      qv[2] = *(const f32x4*)p1;
      qv[3] = *(const f32x4*)(p1 + 4);
    };
    auto store_q = [&](int buf, const f32x4 qv[4]) {
      s16x8 h0, h1;
#pragma unroll
      for (int j = 0; j < 4; ++j) {
        h0[j] = (short)bfrn(qv[0][j]);
        h0[4 + j] = (short)bfrn(qv[1][j]);
        h1[j] = (short)bfrn(qv[2][j]);
        h1[4 + j] = (short)bfrn(qv[3][j]);
      }
      *(s16x8*)&lds[LQS + buf * 8192 + tid * 8] = h0;
      *(s16x8*)&lds[LQS + buf * 8192 + 4096 + tid * 8] = h1;
    };

    {
      f32x4 qv[4];
      load_q(0, qv);
      stage_m(0, 0);
      store_q(0, qv);
    }
    __syncthreads();
    int qb = 0;
    for (int kk = 0; kk < 8; ++kk) {
      f32x4 qv[4];
      if (kk < 7) {
        load_q(kk + 1, qv);
        stage_m(qb ^ 1, kk + 1);
      }
#pragma unroll
      for (int ks2 = 0; ks2 < 2; ++ks2) {
        s16x8 am[4], bq[2];
#pragma unroll
        for (int mi = 0; mi < 4; ++mi) {
          int row = cw * 64 + mi * 16 + l15;
          am[mi] = *(const s16x8*)&lds[LMS + qb * 8192 + row * 64 +
                                       (((ks2 * 4 + g) ^ (row & 7)) << 3)];
        }
#pragma unroll
        for (int ni = 0; ni < 2; ++ni) {
          int row = qw * 32 + ni * 16 + l15;
          bq[ni] = *(const s16x8*)&lds[LQS + qb * 8192 + row * 64 +
                                       (((ks2 * 4 + g) ^ (row & 7)) << 3)];
        }
#pragma unroll
        for (int mi = 0; mi < 4; ++mi)
#pragma unroll
          for (int ni = 0; ni < 2; ++ni) S[mi][ni] = MFMA(am[mi], bq[ni], S[mi][ni]);
      }
      if (kk < 7) store_q(qb ^ 1, qv);
      __syncthreads();
      qb ^= 1;
    }

    auto stage_mt = [&](int buf, int u) {
      int ds = u >> 1, hh = u & 1;
      const ush* src = nmT + (size_t)(ds * 128) * CAPn + cBase + hh * 64;
      gl16(&src[(size_t)r0 * CAPn + usw], &lds[LMT + buf * 8192 + w * 512]);
      gl16(&src[(size_t)(r0 + 64) * CAPn + usw], &lds[LMT + buf * 8192 + 4096 + w * 512]);
    };

    float zl[2] = {0.f, 0.f};
#pragma unroll
    for (int ni = 0; ni < 2; ++ni) {
      int q = qw * 32 + ni * 16 + l15;
#pragma unroll
      for (int mi = 0; mi < 4; ++mi) {
        s16x4 p;
#pragma unroll
        for (int r = 0; r < 4; ++r) {
          float e = __expf(S[mi][ni][r] * SCALE);
          zl[ni] += e;
          p[r] = (short)bfrn(e);
        }
        int u16 = (cw * 8 + mi * 2 + (g >> 1)) ^ (q & 15);
        *(s16x4*)&lds[LPS + q * 128 + u16 * 8 + (g & 1) * 4] = p;
      }
      float v = zl[ni];
      v += __shfl_xor(v, 16);
      v += __shfl_xor(v, 32);
      if (g == 0) zred[((cw * 4 + qw) * 2 + ni) * 16 + l15] = v;
    }
    stage_mt(0, 0);
    __syncthreads();
    if (tid < 128) {
      int qw2 = tid >> 5, ni2 = (tid >> 4) & 1, lq = tid & 15;
      zacc[tid] += zred[((qw2)*2 + ni2) * 16 + lq] + zred[((4 + qw2) * 2 + ni2) * 16 + lq];
    }

    int mb = 0;
#pragma unroll
    for (int u = 0; u < 8; ++u) {
      const int ds = u >> 1, hh = u & 1;
      if (u < 7) stage_mt(mb ^ 1, u + 1);
#pragma unroll
      for (int kc = 0; kc < 2; ++kc) {
        s16x8 am[4], pb[2];
#pragma unroll
        for (int mi = 0; mi < 4; ++mi) {
          int row = cw * 64 + mi * 16 + l15;
          am[mi] = *(const s16x8*)&lds[LMT + mb * 8192 + row * 64 +
                                       (((kc * 4 + g) ^ (row & 7)) << 3)];
        }
#pragma unroll
        for (int ni = 0; ni < 2; ++ni) {
          int q = qw * 32 + ni * 16 + l15;
          int u16 = (hh * 8 + kc * 4 + g) ^ (q & 15);
          pb[ni] = *(const s16x8*)&lds[LPS + q * 128 + u16 * 8];
        }
#pragma unroll
        for (int mi = 0; mi < 4; ++mi)
#pragma unroll
          for (int ni = 0; ni < 2; ++ni)
            O[ds][mi][ni] = MFMA(am[mi], pb[ni], O[ds][mi][ni]);
      }
      __syncthreads();
      mb ^= 1;
    }
  }

  if (tid < 128) zp2[(size_t)cy * ROWS + qBase + tid] = zacc[tid];
#pragma unroll
  for (int ds = 0; ds < 4; ++ds) {
    __syncthreads();
#pragma unroll
    for (int ni = 0; ni < 2; ++ni) {
      int q = qw * 32 + ni * 16 + l15;
#pragma unroll
      for (int mi = 0; mi < 4; ++mi) {
        s16x4 ov;
#pragma unroll
        for (int r = 0; r < 4; ++r) ov[r] = (short)bfrn(O[ds][mi][ni][r]);
        int u16 = (cw * 8 + mi * 2 + (g >> 1)) ^ (q & 15);
        *(s16x4*)&lds[LPS + q * 128 + u16 * 8 + (g & 1) * 4] = ov;
      }
    }
    __syncthreads();
#pragma unroll
    for (int i = 0; i < 4; ++i) {
      int slot = i * 512 + tid;
      int q = slot >> 4, u16 = slot & 15;
      s16x8 v = *(const s16x8*)&lds[LPS + q * 128 + ((u16 ^ (q & 15)) << 3)];
      *(s16x8*)&opart[((size_t)cy * ROWS + qBase + q) * Dn + ds * 128 + u16 * 8] = v;
    }
  }
}

// out = (sum_cy opart[cy]) / (sum_cy zp2[cy]) per row
__global__ void k_merge(const ush* __restrict__ opart, const float* __restrict__ zp2,
                        float* __restrict__ out) {
  size_t i = ((size_t)blockIdx.x * 256 + threadIdx.x) * 4;
  int row = (int)(i >> 9);
  float z = 0.f;
#pragma unroll
  for (int cyy = 0; cyy < 8; ++cyy) z += zp2[(size_t)cyy * ROWS + row];
  float inv = 1.0f / z;
  f32x4 acc = {0.f, 0.f, 0.f, 0.f};
#pragma unroll
  for (int cyy = 0; cyy < 8; ++cyy) {
    s16x4 a = *(const s16x4*)&opart[(size_t)cyy * ROWS * Dn + i];
#pragma unroll
    for (int j = 0; j < 4; ++j) acc[j] += bff((ush)a[j]);
  }
#pragma unroll
  for (int j = 0; j < 4; ++j) acc[j] *= inv;
  *(f32x4*)&out[i] = acc;
}

extern "C" void kernel_launch(void* const* d_in, const int* in_sizes, int n_in,
                              void* d_out, int out_size, void* d_ws, size_t ws_size,
                              hipStream_t stream) {
  const float* keys = (const float*)d_in[0];
  const float* values = (const float*)d_in[1];
  const float* importance = (const float*)d_in[2];
  const float* query = (const float*)d_in[3];
  const float* mem = (const float*)d_in[4];
  char* wsb = (char*)d_ws;
  ush* nm    = (ush*)(wsb + OFF_NM);
  ush* nmT   = (ush*)(wsb + OFF_NMT);
  ush* mlo   = (ush*)(wsb + OFF_NM);   // alias (dead after k_usage)
  ush* mhi   = (ush*)(wsb + OFF_NMT);  // alias (dead after k_usage)
  ush* khi   = (ush*)(wsb + OFF_KHI);
  ush* klo   = (ush*)(wsb + OFF_KLO);
  ush* opart = (ush*)(wsb + OFF_OPART);
  float* zpart = (float*)(wsb + OFF_ZPART);
  float* prio  = (float*)(wsb + OFF_PRIO);
  int* rank    = (int*)(wsb + OFF_RANK);
  float* comb  = (float*)(wsb + OFF_COMB);
  float* zp2   = (float*)(wsb + OFF_ZP2);
  float* invl1 = (float*)(wsb + OFF_COMB + 64);
  float* out = (float*)d_out;

  k_combined<<<Bn, 256, 0, stream>>>(importance, comb);
  k_cvt_hilo<<<(ROWS * Dn / 4) / 256, 256, 0, stream>>>(keys, khi, klo);
  k_cvt_hilo<<<(CAPn * Dn / 4) / 256, 256, 0, stream>>>(mem, mhi, mlo);
  k_rowexp<false><<<CAPn / 64, 256, 0, stream>>>(mhi, khi, zpart);
  k_invl<<<ROWS / 256, 256, 0, stream>>>(zpart, invl1);
  k_usage<<<dim3(CAPn / 128, Bn), 256, 0, stream>>>(mhi, mlo, khi, klo, invl1, comb, prio);
  k_rankinit<<<(Bn * CAPn) / 256, 256, 0, stream>>>(rank);
  k_select<<<Bn, 1024, 0, stream>>>(prio, rank);
  k_newmem<<<(CAPn * Dn / 4) / 256, 256, 0, stream>>>(mem, values, rank, nm);
  k_nmT<<<dim3(CAPn / 64, Dn / 64), 256, 0, stream>>>(nm, nmT);
  k_attnout<<<dim3(ROWS / 128, 8), 512, 0, stream>>>(query, nm, nmT, opart, zp2);
  k_merge<<<(ROWS * Dn / 4) / 256, 256, 0, stream>>>(opart, zp2, out);
}

// Round 5
// 1138.854 us; speedup vs baseline: 12.1330x; 1.0827x over previous
//
#include <hip/hip_runtime.h>

typedef float f32x4 __attribute__((ext_vector_type(4)));
typedef short s16x8 __attribute__((ext_vector_type(8)));
typedef short s16x4 __attribute__((ext_vector_type(4)));
typedef unsigned short ush;

constexpr int Bn = 4, Tn = 1024, Dn = 512, CAPn = 32768, Kn = 1024;
constexpr int ROWS = Bn * Tn; // 4096
constexpr float SCALE = 0.044194173824159216f; // 1/sqrt(512)
constexpr float MOM = 0.99f;
constexpr float RATE_B = 0.0025f; // 0.01 / B

// ---- workspace layout (byte offsets). Total 100.79e6 B (proven ws >= 102.0e6 B) ----
constexpr size_t OFF_NM    = 0;                      // bf16 [CAP][D] (alias: mem_lo early)
constexpr size_t OFF_NMT   = 33554432;               // bf16 [D][CAP] (alias: mem_hi early)
constexpr size_t OFF_OPART = 67108864;               // bf16 [8][ROWS][D] (late)  -- UNION with:
constexpr size_t OFF_KHI   = 67108864;               //   bf16 [ROWS][D] (early)
constexpr size_t OFF_KLO   = 71303168;               //   bf16 [ROWS][D] (early)
constexpr size_t OFF_ZPART = 75497472;               //   f32 [512][ROWS] (early)
constexpr size_t OFF_PRIO  = 83886080;               //   f32 [4][CAP] (early)
constexpr size_t OFF_RANK  = 84410368;               //   i32 [4][CAP] (early)
constexpr size_t OFF_COMB  = 84934656;               //   f32 [4] (early)
constexpr size_t OFF_ZP2   = 100663296;              // f32 [8][ROWS] (late)

#define MFMA(a, b, c) __builtin_amdgcn_mfma_f32_16x16x32_bf16((a), (b), (c), 0, 0, 0)

__device__ __forceinline__ ush bfrn(float x) {
  unsigned u = __float_as_uint(x);
  return (ush)((u + 0x7FFFu + ((u >> 16) & 1u)) >> 16);
}
__device__ __forceinline__ float bff(ush h) { return __uint_as_float(((unsigned)h) << 16); }

__device__ __forceinline__ void gl16(const ush* g, ush* l) {
  __builtin_amdgcn_global_load_lds(
      (const __attribute__((address_space(1))) void*)(uintptr_t)g,
      (__attribute__((address_space(3))) void*)(uintptr_t)l, 16, 0, 0);
}

// combined[b] = mean(importance[b,:,0])
__global__ void k_combined(const float* __restrict__ imp, float* __restrict__ comb) {
  __shared__ float red[256];
  int b = blockIdx.x;
  float s = 0.f;
  for (int t = threadIdx.x; t < Tn; t += 256) s += imp[(size_t)b * Tn + t];
  red[threadIdx.x] = s;
  __syncthreads();
  for (int off = 128; off > 0; off >>= 1) {
    if (threadIdx.x < (unsigned)off) red[threadIdx.x] += red[threadIdx.x + off];
    __syncthreads();
  }
  if (threadIdx.x == 0) comb[b] = red[0] * (1.0f / Tn);
}

// x -> hi (RTN bf16), lo (RTN bf16 of residual). 4 elems/thread.
__global__ void k_cvt_hilo(const float* __restrict__ x, ush* __restrict__ hi,
                           ush* __restrict__ lo) {
  size_t i = ((size_t)blockIdx.x * 256 + threadIdx.x) * 4;
  f32x4 v = *(const f32x4*)&x[i];
  s16x4 h, l;
#pragma unroll
  for (int j = 0; j < 4; ++j) {
    ush hh = bfrn(v[j]);
    h[j] = (short)hh;
    l[j] = (short)bfrn(v[j] - bff(hh));
  }
  *(s16x4*)&hi[i] = h;
  *(s16x4*)&lo[i] = l;
}

// Z partials: zpart[cb][t] = sum over this block's 64 c of exp(A[c,:].B[t,:])
// A rows in registers; B staged via global_load_lds (pre-swizzled src, linear dst).
__global__ __launch_bounds__(256, 2) void k_rowexp(const ush* __restrict__ Abf,
                                                   const ush* __restrict__ Bbf,
                                                   float* __restrict__ zpart) {
  __shared__ ush Bs[64 * 512];
  __shared__ float red[2][64];
  const int tid = threadIdx.x;
  const int lane = tid & 63, wid = tid >> 6;
  const int wc2 = wid >> 1, wt = wid & 1;
  const int l15 = lane & 15, g = lane >> 4;
  const int cb = blockIdx.x;
  const int cBase = cb * 64;

  s16x8 afr[2][16];
#pragma unroll
  for (int mi = 0; mi < 2; ++mi) {
    int c = cBase + wc2 * 32 + mi * 16 + l15;
#pragma unroll
    for (int ks = 0; ks < 16; ++ks)
      afr[mi][ks] = *(const s16x8*)&Abf[(size_t)c * Dn + ks * 32 + g * 8];
  }

  for (int tt = 0; tt < 64; ++tt) {
    const int tBase = tt * 64;
#pragma unroll
    for (int rr = 0; rr < 16; ++rr) {
      int idx = rr * 256 + tid;
      int row = idx >> 6, ch = idx & 63;
      gl16(&Bbf[(size_t)(tBase + row) * Dn + ((ch ^ (row & 7)) << 3)],
           &Bs[rr * 2048 + wid * 512]);
    }
    __syncthreads();
    f32x4 S[2][2];
#pragma unroll
    for (int mi = 0; mi < 2; ++mi)
#pragma unroll
      for (int ni = 0; ni < 2; ++ni) S[mi][ni] = (f32x4){0.f, 0.f, 0.f, 0.f};
#pragma unroll
    for (int ks = 0; ks < 16; ++ks) {
      s16x8 bfr[2];
#pragma unroll
      for (int ni = 0; ni < 2; ++ni) {
        int trow = wt * 32 + ni * 16 + l15;
        bfr[ni] = *(const s16x8*)&Bs[trow * 512 + (((ks * 4 + g) ^ (trow & 7)) * 8)];
      }
#pragma unroll
      for (int mi = 0; mi < 2; ++mi)
#pragma unroll
        for (int ni = 0; ni < 2; ++ni) S[mi][ni] = MFMA(afr[mi][ks], bfr[ni], S[mi][ni]);
    }
    float tacc[2] = {0.f, 0.f};
#pragma unroll
    for (int mi = 0; mi < 2; ++mi)
#pragma unroll
      for (int ni = 0; ni < 2; ++ni)
#pragma unroll
        for (int r = 0; r < 4; ++r) tacc[ni] += __expf(S[mi][ni][r]);
#pragma unroll
    for (int ni = 0; ni < 2; ++ni) {
      float v = tacc[ni];
      v += __shfl_xor(v, 16);
      v += __shfl_xor(v, 32);
      tacc[ni] = v;
    }
    if (g == 0) {
      red[wc2][wt * 32 + l15] = tacc[0];
      red[wc2][wt * 32 + 16 + l15] = tacc[1];
    }
    __syncthreads();
    if (tid < 64) zpart[(size_t)cb * ROWS + tBase + tid] = red[0][tid] + red[1][tid];
  }
}

__global__ void k_invl(const float* __restrict__ zpart, float* __restrict__ invl) {
  int t = blockIdx.x * 256 + threadIdx.x;
  float s = 0.f;
  for (int cb = 0; cb < 512; ++cb) s += zpart[(size_t)cb * ROWS + t];
  invl[t] = 1.0f / s;
}

// prio[b,c] = comb[b] + 0.1 * sum_t exp(scores[b,t,c]) * invl1[b,t]
// 3-term compensated bf16 GEMM; staging via global_load_lds.
__global__ __launch_bounds__(256, 2) void k_usage(const ush* __restrict__ mhi,
                                                  const ush* __restrict__ mlo,
                                                  const ush* __restrict__ khi,
                                                  const ush* __restrict__ klo,
                                                  const float* __restrict__ invl,
                                                  const float* __restrict__ comb,
                                                  float* __restrict__ prio) {
  __shared__ ush Ahi[128 * 64], Alo[128 * 64], Bhi[128 * 64], Blo[128 * 64];
  const int tid = threadIdx.x;
  const int lane = tid & 63, w = tid >> 6;
  const int l15 = lane & 15, g = lane >> 4;
  const int cBase = blockIdx.x * 128;
  const int b = blockIdx.y;
  const ush* khb = khi + (size_t)b * Tn * Dn;
  const ush* klb = klo + (size_t)b * Tn * Dn;
  const int r0 = tid >> 3, u0 = tid & 7;
  const int usw = (u0 ^ (r0 & 7)) << 3;

  float uacc[2][4] = {{0.f, 0.f, 0.f, 0.f}, {0.f, 0.f, 0.f, 0.f}};
  for (int tt = 0; tt < 8; ++tt) {
    f32x4 S[2][8];
#pragma unroll
    for (int mi = 0; mi < 2; ++mi)
#pragma unroll
      for (int ni = 0; ni < 8; ++ni) S[mi][ni] = (f32x4){0.f, 0.f, 0.f, 0.f};
    for (int kk = 0; kk < 8; ++kk) {
      __syncthreads();
      {
        size_t a0 = (size_t)(cBase + r0) * Dn + kk * 64 + usw;
        size_t a1 = (size_t)(cBase + r0 + 64) * Dn + kk * 64 + usw;
        gl16(&mhi[a0], &Ahi[w * 512]);
        gl16(&mhi[a1], &Ahi[4096 + w * 512]);
        gl16(&mlo[a0], &Alo[w * 512]);
        gl16(&mlo[a1], &Alo[4096 + w * 512]);
        size_t b0 = (size_t)(tt * 128 + r0) * Dn + kk * 64 + usw;
        size_t b1 = (size_t)(tt * 128 + r0 + 64) * Dn + kk * 64 + usw;
        gl16(&khb[b0], &Bhi[w * 512]);
        gl16(&khb[b1], &Bhi[4096 + w * 512]);
        gl16(&klb[b0], &Blo[w * 512]);
        gl16(&klb[b1], &Blo[4096 + w * 512]);
      }
      __syncthreads();
#pragma unroll
      for (int ks2 = 0; ks2 < 2; ++ks2) {
        s16x8 ah[2], al[2];
#pragma unroll
        for (int mi = 0; mi < 2; ++mi) {
          int crow = w * 32 + mi * 16 + l15;
          int addr = crow * 64 + (((ks2 * 4 + g) ^ (crow & 7)) * 8);
          ah[mi] = *(const s16x8*)&Ahi[addr];
          al[mi] = *(const s16x8*)&Alo[addr];
        }
#pragma unroll
        for (int ni = 0; ni < 8; ++ni) {
          int trow = ni * 16 + l15;
          int addr = trow * 64 + (((ks2 * 4 + g) ^ (trow & 7)) * 8);
          s16x8 bh = *(const s16x8*)&Bhi[addr];
          s16x8 bl = *(const s16x8*)&Blo[addr];
#pragma unroll
          for (int mi = 0; mi < 2; ++mi) {
            S[mi][ni] = MFMA(ah[mi], bh, S[mi][ni]);
            S[mi][ni] = MFMA(ah[mi], bl, S[mi][ni]);
            S[mi][ni] = MFMA(al[mi], bh, S[mi][ni]);
          }
        }
      }
    }
#pragma unroll
    for (int ni = 0; ni < 8; ++ni) {
      float il = invl[b * Tn + tt * 128 + ni * 16 + l15];
#pragma unroll
      for (int mi = 0; mi < 2; ++mi)
#pragma unroll
        for (int r = 0; r < 4; ++r) uacc[mi][r] += __expf(S[mi][ni][r]) * il;
    }
  }
#pragma unroll
  for (int mi = 0; mi < 2; ++mi)
#pragma unroll
    for (int r = 0; r < 4; ++r) {
      float v = uacc[mi][r];
      v += __shfl_xor(v, 1);
      v += __shfl_xor(v, 2);
      v += __shfl_xor(v, 4);
      v += __shfl_xor(v, 8);
      if (l15 == 0)
        prio[(size_t)b * CAPn + cBase + w * 32 + mi * 16 + g * 4 + r] =
            comb[b] + 0.1f * v;
    }
}

// rank init: unselected slots get Kn (k_newmem tests r < Kn)
__global__ void k_rankinit(int* __restrict__ rank) {
  rank[blockIdx.x * 256 + threadIdx.x] = Kn;
}

// Per-batch exact top-K selection + stable rank (jax top_k semantics).
__global__ __launch_bounds__(1024) void k_select(const float* __restrict__ prio,
                                                 int* __restrict__ rank) {
  const int b = blockIdx.x;
  const float* p = prio + (size_t)b * CAPn;
  __shared__ int hist[256];
  __shared__ unsigned long long s_pref;
  __shared__ int s_krem;
  __shared__ int s_cnt;
  __shared__ unsigned long long selk[Kn];
  const int tid = threadIdx.x;
  if (tid == 0) { s_pref = 0ull; s_krem = Kn; s_cnt = 0; }

#define KEYOF(c, kk)                                                         \
  {                                                                          \
    unsigned mb_ = __float_as_uint(p[(c)]);                                  \
    mb_ = (mb_ & 0x80000000u) ? ~mb_ : (mb_ | 0x80000000u);                  \
    (kk) = ((unsigned long long)mb_ << 32) | (unsigned)(0xFFFFFFFFu - (c));  \
  }

  __syncthreads();
  for (int pos = 56; pos >= 0; pos -= 8) {
    if (tid < 256) hist[tid] = 0;
    __syncthreads();
    unsigned long long pref = s_pref;
    unsigned long long maskhi = (pos == 56) ? 0ull : (~0ull << (pos + 8));
    for (int c = tid; c < CAPn; c += 1024) {
      unsigned long long k;
      KEYOF(c, k);
      if ((k & maskhi) == pref) atomicAdd(&hist[(int)((k >> pos) & 255)], 1);
    }
    __syncthreads();
    if (tid == 0) {
      int krem = s_krem;
      int d = 255;
      for (;; --d) {
        int h = hist[d];
        if (krem <= h || d == 0) break;
        krem -= h;
      }
      s_pref = pref | ((unsigned long long)d << pos);
      s_krem = krem;
    }
    __syncthreads();
  }
  unsigned long long T = s_pref;  // exact Kn-th largest key
  for (int c = tid; c < CAPn; c += 1024) {
    unsigned long long k;
    KEYOF(c, k);
    if (k >= T) {
      int idx = atomicAdd(&s_cnt, 1);
      selk[idx] = k;
    }
  }
  __syncthreads();
  unsigned long long mine = selk[tid];
  int r = 0;
  for (int j = 0; j < Kn; ++j) r += (selk[j] > mine) ? 1 : 0;
  int c = (int)(0xFFFFFFFFu - (unsigned)(mine & 0xFFFFFFFFull));
  rank[(size_t)b * CAPn + c] = r;
#undef KEYOF
}

// new_mem (bf16) = 0.99*mem + 0.0025 * sum_b (rank_b[c] < K ? values[b, rank_b[c], :] : 0)
__global__ void k_newmem(const float* __restrict__ mem, const float* __restrict__ values,
                         const int* __restrict__ rank, ush* __restrict__ nm) {
  int gid = blockIdx.x * 256 + threadIdx.x;
  int c = gid >> 7;
  int q = (gid & 127) << 2;
  f32x4 m = *(const f32x4*)&mem[(size_t)c * Dn + q];
  f32x4 acc = {0.f, 0.f, 0.f, 0.f};
#pragma unroll
  for (int b = 0; b < Bn; ++b) {
    int r = rank[(size_t)b * CAPn + c];
    if (r < Kn) acc += *(const f32x4*)&values[((size_t)b * Tn + r) * Dn + q];
  }
  f32x4 res = m * MOM + acc * RATE_B;
  s16x4 o;
#pragma unroll
  for (int j = 0; j < 4; ++j) o[j] = (short)bfrn(res[j]);
  *(s16x4*)&nm[(size_t)c * Dn + q] = o;
}

// nmT[d][c] = nm[c][d]
__global__ void k_nmT(const ush* __restrict__ nm, ush* __restrict__ nmT) {
  __shared__ ush tile[64][65];
  int cBase = blockIdx.x * 64, dBase = blockIdx.y * 64;
  int tid = threadIdx.x;
#pragma unroll
  for (int rr = 0; rr < 2; ++rr) {
    int idx = rr * 256 + tid;
    int row = idx >> 3, ch = idx & 7;
    s16x8 v = *(const s16x8*)&nm[(size_t)(cBase + row) * Dn + dBase + ch * 8];
#pragma unroll
    for (int j = 0; j < 8; ++j) tile[row][ch * 8 + j] = (ush)v[j];
  }
  __syncthreads();
#pragma unroll
  for (int rr = 0; rr < 2; ++rr) {
    int idx = rr * 256 + tid;
    int drow = idx >> 3, ch = idx & 7;
    s16x8 v;
#pragma unroll
    for (int j = 0; j < 8; ++j) v[j] = (short)tile[ch * 8 + j][drow];
    *(s16x8*)&nmT[(size_t)(dBase + drow) * CAPn + cBase + ch * 8] = v;
  }
}

// Fused attn: grid (8 cy, 32 q-tiles) -> all blocks of one cy share an XCD.
// 8 waves x 16 q-rows each, Q fragments in registers (no Q reload/LDS).
// opart[cy] = sum_c exp(S*scale)_bf16 * M,  zp2[cy][q] = sum_c exp(S*scale).
// LDS 96KB: Ms dbuf [2][128][64] @0, Mt dbuf [2][128][64] @16384, Ps[128][128] @32768.
__global__ __launch_bounds__(512, 1) void k_attnout(
    const float* __restrict__ query, const ush* __restrict__ nm,
    const ush* __restrict__ nmT, ush* __restrict__ opart,
    float* __restrict__ zp2) {
  __shared__ ush lds[49152];
  __shared__ float zred[128];
  __shared__ float zacc[128];
  constexpr int LMS = 0, LMT = 16384, LPS = 32768;
  const int tid = threadIdx.x;
  const int lane = tid & 63, w = tid >> 6;
  const int l15 = lane & 15, g = lane >> 4;
  const int cy = blockIdx.x;
  const int qBase = blockIdx.y * 128;
  const int q = w * 16 + l15;  // block-relative q row owned by this lane (MFMA col)
  const int r0 = tid >> 3, u0 = tid & 7;
  const int usw = (u0 ^ (r0 & 7)) << 3;

  // Q fragments in registers: row qBase+q, full K=512, converted once.
  s16x8 qfr[16];
  {
    const float* qsrc = query + (size_t)(qBase + q) * Dn;
#pragma unroll
    for (int ks = 0; ks < 16; ++ks) {
      f32x4 a = *(const f32x4*)&qsrc[ks * 32 + g * 8];
      f32x4 b = *(const f32x4*)&qsrc[ks * 32 + g * 8 + 4];
      s16x8 h;
#pragma unroll
      for (int j = 0; j < 4; ++j) {
        h[j] = (short)bfrn(a[j]);
        h[4 + j] = (short)bfrn(b[j]);
      }
      qfr[ks] = h;
    }
  }

  f32x4 O[32];  // O^T acc: d = ds*128 + mi*16 + g*4 + r (idx = ds*8+mi), col q
#pragma unroll
  for (int i = 0; i < 32; ++i) O[i] = (f32x4){0.f, 0.f, 0.f, 0.f};
  if (tid < 128) zacc[tid] = 0.f;

  for (int ct = 0; ct < 32; ++ct) {
    const int cBase = cy * 4096 + ct * 128;

    auto stage_m = [&](int buf, int kk) {
      const ush* src = nm + (size_t)cBase * Dn + kk * 64;
      gl16(&src[(size_t)r0 * Dn + usw], &lds[LMS + buf * 8192 + w * 512]);
      gl16(&src[(size_t)(r0 + 64) * Dn + usw], &lds[LMS + buf * 8192 + 4096 + w * 512]);
    };
    auto stage_mt = [&](int buf, int u) {
      const ush* src = nmT + (size_t)((u >> 1) * 128) * CAPn + cBase + (u & 1) * 64;
      gl16(&src[(size_t)r0 * CAPn + usw], &lds[LMT + buf * 8192 + w * 512]);
      gl16(&src[(size_t)(r0 + 64) * CAPn + usw], &lds[LMT + buf * 8192 + 4096 + w * 512]);
    };

    // ---- QK: S^T[c 128][q 128], K=512, dbuf ----
    f32x4 S[8];
#pragma unroll
    for (int i = 0; i < 8; ++i) S[i] = (f32x4){0.f, 0.f, 0.f, 0.f};
    stage_m(0, 0);
    __syncthreads();
#pragma unroll
    for (int kk = 0; kk < 8; ++kk) {
      if (kk < 7) stage_m((kk + 1) & 1, kk + 1);
#pragma unroll
      for (int ks2 = 0; ks2 < 2; ++ks2) {
#pragma unroll
        for (int mi = 0; mi < 8; ++mi) {
          int row = mi * 16 + l15;
          s16x8 am = *(const s16x8*)&lds[LMS + (kk & 1) * 8192 + row * 64 +
                                         (((ks2 * 4 + g) ^ (row & 7)) << 3)];
          S[mi] = MFMA(am, qfr[kk * 2 + ks2], S[mi]);
        }
      }
      __syncthreads();
    }

    // ---- P = exp(S*SCALE) (unnormalized) -> Ps; z partial ----
    float zl = 0.f;
#pragma unroll
    for (int mi = 0; mi < 8; ++mi) {
      s16x4 p;
#pragma unroll
      for (int r = 0; r < 4; ++r) {
        float e = __expf(S[mi][r] * SCALE);
        zl += e;
        p[r] = (short)bfrn(e);
      }
      int u16 = (mi * 2 + (g >> 1)) ^ l15;
      *(s16x4*)&lds[LPS + q * 128 + u16 * 8 + (g & 1) * 4] = p;
    }
    zl += __shfl_xor(zl, 16);
    zl += __shfl_xor(zl, 32);
    if (g == 0) zred[q] = zl;
    stage_mt(0, 0);
    __syncthreads();
    if (tid < 128) zacc[tid] += zred[tid];

    // ---- PV: O^T[d 512][q 128] over this ct's 128 c, dbuf ----
#pragma unroll
    for (int u = 0; u < 8; ++u) {
      if (u < 7) stage_mt((u + 1) & 1, u + 1);
      const int hh = u & 1;
#pragma unroll
      for (int kc = 0; kc < 2; ++kc) {
        int u16 = (hh * 8 + kc * 4 + g) ^ l15;
        s16x8 pb = *(const s16x8*)&lds[LPS + q * 128 + u16 * 8];
#pragma unroll
        for (int mi = 0; mi < 8; ++mi) {
          int row = mi * 16 + l15;
          s16x8 am = *(const s16x8*)&lds[LMT + (u & 1) * 8192 + row * 64 +
                                         (((kc * 4 + g) ^ (row & 7)) << 3)];
          O[(u >> 1) * 8 + mi] = MFMA(am, pb, O[(u >> 1) * 8 + mi]);
        }
      }
      __syncthreads();
    }
  }

  // ---- epilogue: z store + O transpose through LDS for coalesced stores ----
  if (tid < 128) zp2[(size_t)cy * ROWS + qBase + tid] = zacc[tid];
#pragma unroll
  for (int ds = 0; ds < 4; ++ds) {
    __syncthreads();
#pragma unroll
    for (int mi = 0; mi < 8; ++mi) {
      s16x4 ov;
#pragma unroll
      for (int r = 0; r < 4; ++r) ov[r] = (short)bfrn(O[ds * 8 + mi][r]);
      int u16 = (mi * 2 + (g >> 1)) ^ l15;
      *(s16x4*)&lds[LPS + q * 128 + u16 * 8 + (g & 1) * 4] = ov;
    }
    __syncthreads();
#pragma unroll
    for (int i = 0; i < 4; ++i) {
      int slot = i * 512 + tid;
      int qq = slot >> 4, u16 = slot & 15;
      s16x8 v = *(const s16x8*)&lds[LPS + qq * 128 + ((u16 ^ (qq & 15)) << 3)];
      *(s16x8*)&opart[((size_t)cy * ROWS + qBase + qq) * Dn + ds * 128 + u16 * 8] = v;
    }
  }
}

// out = (sum_cy opart[cy]) / (sum_cy zp2[cy]) per row
__global__ void k_merge(const ush* __restrict__ opart, const float* __restrict__ zp2,
                        float* __restrict__ out) {
  size_t i = ((size_t)blockIdx.x * 256 + threadIdx.x) * 4;
  int row = (int)(i >> 9);
  float z = 0.f;
#pragma unroll
  for (int cyy = 0; cyy < 8; ++cyy) z += zp2[(size_t)cyy * ROWS + row];
  float inv = 1.0f / z;
  f32x4 acc = {0.f, 0.f, 0.f, 0.f};
#pragma unroll
  for (int cyy = 0; cyy < 8; ++cyy) {
    s16x4 a = *(const s16x4*)&opart[(size_t)cyy * ROWS * Dn + i];
#pragma unroll
    for (int j = 0; j < 4; ++j) acc[j] += bff((ush)a[j]);
  }
#pragma unroll
  for (int j = 0; j < 4; ++j) acc[j] *= inv;
  *(f32x4*)&out[i] = acc;
}

extern "C" void kernel_launch(void* const* d_in, const int* in_sizes, int n_in,
                              void* d_out, int out_size, void* d_ws, size_t ws_size,
                              hipStream_t stream) {
  const float* keys = (const float*)d_in[0];
  const float* values = (const float*)d_in[1];
  const float* importance = (const float*)d_in[2];
  const float* query = (const float*)d_in[3];
  const float* mem = (const float*)d_in[4];
  char* wsb = (char*)d_ws;
  ush* nm    = (ush*)(wsb + OFF_NM);
  ush* nmT   = (ush*)(wsb + OFF_NMT);
  ush* mlo   = (ush*)(wsb + OFF_NM);   // alias (dead after k_usage)
  ush* mhi   = (ush*)(wsb + OFF_NMT);  // alias (dead after k_usage)
  ush* khi   = (ush*)(wsb + OFF_KHI);
  ush* klo   = (ush*)(wsb + OFF_KLO);
  ush* opart = (ush*)(wsb + OFF_OPART);
  float* zpart = (float*)(wsb + OFF_ZPART);
  float* prio  = (float*)(wsb + OFF_PRIO);
  int* rank    = (int*)(wsb + OFF_RANK);
  float* comb  = (float*)(wsb + OFF_COMB);
  float* zp2   = (float*)(wsb + OFF_ZP2);
  float* invl1 = (float*)(wsb + OFF_COMB + 64);
  float* out = (float*)d_out;

  k_combined<<<Bn, 256, 0, stream>>>(importance, comb);
  k_cvt_hilo<<<(ROWS * Dn / 4) / 256, 256, 0, stream>>>(keys, khi, klo);
  k_cvt_hilo<<<(CAPn * Dn / 4) / 256, 256, 0, stream>>>(mem, mhi, mlo);
  k_rowexp<<<CAPn / 64, 256, 0, stream>>>(mhi, khi, zpart);
  k_invl<<<ROWS / 256, 256, 0, stream>>>(zpart, invl1);
  k_usage<<<dim3(CAPn / 128, Bn), 256, 0, stream>>>(mhi, mlo, khi, klo, invl1, comb, prio);
  k_rankinit<<<(Bn * CAPn) / 256, 256, 0, stream>>>(rank);
  k_select<<<Bn, 1024, 0, stream>>>(prio, rank);
  k_newmem<<<(CAPn * Dn / 4) / 256, 256, 0, stream>>>(mem, values, rank, nm);
  k_nmT<<<dim3(CAPn / 64, Dn / 64), 256, 0, stream>>>(nm, nmT);
  k_attnout<<<dim3(8, ROWS / 128), 512, 0, stream>>>(query, nm, nmT, opart, zp2);
  k_merge<<<(ROWS * Dn / 4) / 256, 256, 0, stream>>>(opart, zp2, out);
}

// Round 7
// 1122.654 us; speedup vs baseline: 12.3081x; 1.0144x over previous
//
#include <hip/hip_runtime.h>

typedef float f32x4 __attribute__((ext_vector_type(4)));
typedef short s16x8 __attribute__((ext_vector_type(8)));
typedef short s16x4 __attribute__((ext_vector_type(4)));
typedef unsigned short ush;

constexpr int Bn = 4, Tn = 1024, Dn = 512, CAPn = 32768, Kn = 1024;
constexpr int ROWS = Bn * Tn; // 4096
constexpr float SCALE = 0.044194173824159216f; // 1/sqrt(512)
constexpr float MOM = 0.99f;
constexpr float RATE_B = 0.0025f; // 0.01 / B

// ---- workspace layout (byte offsets). Total 100.79e6 B (proven ws >= 102.0e6 B) ----
constexpr size_t OFF_NM    = 0;                      // bf16 [CAP][D] (alias: mem_lo early)
constexpr size_t OFF_NMT   = 33554432;               // bf16 [D][CAP] (alias: mem_hi early)
constexpr size_t OFF_OPART = 67108864;               // bf16 [8][ROWS][D] (late)  -- UNION with:
constexpr size_t OFF_KHI   = 67108864;               //   bf16 [ROWS][D] (early)
constexpr size_t OFF_KLO   = 71303168;               //   bf16 [ROWS][D] (early)
constexpr size_t OFF_ZPART = 75497472;               //   f32 [512][ROWS] (early)
constexpr size_t OFF_PRIO  = 83886080;               //   f32 [4][CAP] (early)
constexpr size_t OFF_RANK  = 84410368;               //   i32 [4][CAP] (early)
constexpr size_t OFF_COMB  = 84934656;               //   f32 [4] (early)
constexpr size_t OFF_ZP2   = 100663296;              // f32 [8][ROWS] (late)

#define MFMA(a, b, c) __builtin_amdgcn_mfma_f32_16x16x32_bf16((a), (b), (c), 0, 0, 0)
#define WAITV2 asm volatile("s_waitcnt vmcnt(2)" ::: "memory")
#define WAITL0 asm volatile("s_waitcnt lgkmcnt(0)" ::: "memory")
#define BAR __builtin_amdgcn_s_barrier()

__device__ __forceinline__ ush bfrn(float x) {
  unsigned u = __float_as_uint(x);
  return (ush)((u + 0x7FFFu + ((u >> 16) & 1u)) >> 16);
}
__device__ __forceinline__ float bff(ush h) { return __uint_as_float(((unsigned)h) << 16); }

__device__ __forceinline__ void gl16(const ush* g, ush* l) {
  __builtin_amdgcn_global_load_lds(
      (const __attribute__((address_space(1))) void*)(uintptr_t)g,
      (__attribute__((address_space(3))) void*)(uintptr_t)l, 16, 0, 0);
}

// combined[b] = mean(importance[b,:,0])
__global__ void k_combined(const float* __restrict__ imp, float* __restrict__ comb) {
  __shared__ float red[256];
  int b = blockIdx.x;
  float s = 0.f;
  for (int t = threadIdx.x; t < Tn; t += 256) s += imp[(size_t)b * Tn + t];
  red[threadIdx.x] = s;
  __syncthreads();
  for (int off = 128; off > 0; off >>= 1) {
    if (threadIdx.x < (unsigned)off) red[threadIdx.x] += red[threadIdx.x + off];
    __syncthreads();
  }
  if (threadIdx.x == 0) comb[b] = red[0] * (1.0f / Tn);
}

// x -> hi (RTN bf16), lo (RTN bf16 of residual). 4 elems/thread.
__global__ void k_cvt_hilo(const float* __restrict__ x, ush* __restrict__ hi,
                           ush* __restrict__ lo) {
  size_t i = ((size_t)blockIdx.x * 256 + threadIdx.x) * 4;
  f32x4 v = *(const f32x4*)&x[i];
  s16x4 h, l;
#pragma unroll
  for (int j = 0; j < 4; ++j) {
    ush hh = bfrn(v[j]);
    h[j] = (short)hh;
    l[j] = (short)bfrn(v[j] - bff(hh));
  }
  *(s16x4*)&hi[i] = h;
  *(s16x4*)&lo[i] = l;
}

// Z partials: zpart[cb][t] = sum over this block's 64 c of exp(A[c,:].B[t,:])
__global__ __launch_bounds__(256, 2) void k_rowexp(const ush* __restrict__ Abf,
                                                   const ush* __restrict__ Bbf,
                                                   float* __restrict__ zpart) {
  __shared__ ush Bs[64 * 512];
  __shared__ float red[2][64];
  const int tid = threadIdx.x;
  const int lane = tid & 63, wid = tid >> 6;
  const int wc2 = wid >> 1, wt = wid & 1;
  const int l15 = lane & 15, g = lane >> 4;
  const int cb = blockIdx.x;
  const int cBase = cb * 64;

  s16x8 afr[2][16];
#pragma unroll
  for (int mi = 0; mi < 2; ++mi) {
    int c = cBase + wc2 * 32 + mi * 16 + l15;
#pragma unroll
    for (int ks = 0; ks < 16; ++ks)
      afr[mi][ks] = *(const s16x8*)&Abf[(size_t)c * Dn + ks * 32 + g * 8];
  }

  for (int tt = 0; tt < 64; ++tt) {
    const int tBase = tt * 64;
#pragma unroll
    for (int rr = 0; rr < 16; ++rr) {
      int idx = rr * 256 + tid;
      int row = idx >> 6, ch = idx & 63;
      gl16(&Bbf[(size_t)(tBase + row) * Dn + ((ch ^ (row & 7)) << 3)],
           &Bs[rr * 2048 + wid * 512]);
    }
    __syncthreads();
    f32x4 S[2][2];
#pragma unroll
    for (int mi = 0; mi < 2; ++mi)
#pragma unroll
      for (int ni = 0; ni < 2; ++ni) S[mi][ni] = (f32x4){0.f, 0.f, 0.f, 0.f};
#pragma unroll
    for (int ks = 0; ks < 16; ++ks) {
      s16x8 bfr[2];
#pragma unroll
      for (int ni = 0; ni < 2; ++ni) {
        int trow = wt * 32 + ni * 16 + l15;
        bfr[ni] = *(const s16x8*)&Bs[trow * 512 + (((ks * 4 + g) ^ (trow & 7)) * 8)];
      }
#pragma unroll
      for (int mi = 0; mi < 2; ++mi)
#pragma unroll
        for (int ni = 0; ni < 2; ++ni) S[mi][ni] = MFMA(afr[mi][ks], bfr[ni], S[mi][ni]);
    }
    float tacc[2] = {0.f, 0.f};
#pragma unroll
    for (int mi = 0; mi < 2; ++mi)
#pragma unroll
      for (int ni = 0; ni < 2; ++ni)
#pragma unroll
        for (int r = 0; r < 4; ++r) tacc[ni] += __expf(S[mi][ni][r]);
#pragma unroll
    for (int ni = 0; ni < 2; ++ni) {
      float v = tacc[ni];
      v += __shfl_xor(v, 16);
      v += __shfl_xor(v, 32);
      tacc[ni] = v;
    }
    if (g == 0) {
      red[wc2][wt * 32 + l15] = tacc[0];
      red[wc2][wt * 32 + 16 + l15] = tacc[1];
    }
    __syncthreads();
    if (tid < 64) zpart[(size_t)cb * ROWS + tBase + tid] = red[0][tid] + red[1][tid];
  }
}

__global__ void k_invl(const float* __restrict__ zpart, float* __restrict__ invl) {
  int t = blockIdx.x * 256 + threadIdx.x;
  float s = 0.f;
  for (int cb = 0; cb < 512; ++cb) s += zpart[(size_t)cb * ROWS + t];
  invl[t] = 1.0f / s;
}

// prio[b,c] = comb[b] + 0.1 * sum_t exp(scores[b,t,c]) * invl1[b,t]
__global__ __launch_bounds__(256, 2) void k_usage(const ush* __restrict__ mhi,
                                                  const ush* __restrict__ mlo,
                                                  const ush* __restrict__ khi,
                                                  const ush* __restrict__ klo,
                                                  const float* __restrict__ invl,
                                                  const float* __restrict__ comb,
                                                  float* __restrict__ prio) {
  __shared__ ush Ahi[128 * 64], Alo[128 * 64], Bhi[128 * 64], Blo[128 * 64];
  const int tid = threadIdx.x;
  const int lane = tid & 63, w = tid >> 6;
  const int l15 = lane & 15, g = lane >> 4;
  const int cBase = blockIdx.x * 128;
  const int b = blockIdx.y;
  const ush* khb = khi + (size_t)b * Tn * Dn;
  const ush* klb = klo + (size_t)b * Tn * Dn;
  const int r0 = tid >> 3, u0 = tid & 7;
  const int usw = (u0 ^ (r0 & 7)) << 3;

  float uacc[2][4] = {{0.f, 0.f, 0.f, 0.f}, {0.f, 0.f, 0.f, 0.f}};
  for (int tt = 0; tt < 8; ++tt) {
    f32x4 S[2][8];
#pragma unroll
    for (int mi = 0; mi < 2; ++mi)
#pragma unroll
      for (int ni = 0; ni < 8; ++ni) S[mi][ni] = (f32x4){0.f, 0.f, 0.f, 0.f};
    for (int kk = 0; kk < 8; ++kk) {
      __syncthreads();
      {
        size_t a0 = (size_t)(cBase + r0) * Dn + kk * 64 + usw;
        size_t a1 = (size_t)(cBase + r0 + 64) * Dn + kk * 64 + usw;
        gl16(&mhi[a0], &Ahi[w * 512]);
        gl16(&mhi[a1], &Ahi[4096 + w * 512]);
        gl16(&mlo[a0], &Alo[w * 512]);
        gl16(&mlo[a1], &Alo[4096 + w * 512]);
        size_t b0 = (size_t)(tt * 128 + r0) * Dn + kk * 64 + usw;
        size_t b1 = (size_t)(tt * 128 + r0 + 64) * Dn + kk * 64 + usw;
        gl16(&khb[b0], &Bhi[w * 512]);
        gl16(&khb[b1], &Bhi[4096 + w * 512]);
        gl16(&klb[b0], &Blo[w * 512]);
        gl16(&klb[b1], &Blo[4096 + w * 512]);
      }
      __syncthreads();
#pragma unroll
      for (int ks2 = 0; ks2 < 2; ++ks2) {
        s16x8 ah[2], al[2];
#pragma unroll
        for (int mi = 0; mi < 2; ++mi) {
          int crow = w * 32 + mi * 16 + l15;
          int addr = crow * 64 + (((ks2 * 4 + g) ^ (crow & 7)) * 8);
          ah[mi] = *(const s16x8*)&Ahi[addr];
          al[mi] = *(const s16x8*)&Alo[addr];
        }
#pragma unroll
        for (int ni = 0; ni < 8; ++ni) {
          int trow = ni * 16 + l15;
          int addr = trow * 64 + (((ks2 * 4 + g) ^ (trow & 7)) * 8);
          s16x8 bh = *(const s16x8*)&Bhi[addr];
          s16x8 bl = *(const s16x8*)&Blo[addr];
#pragma unroll
          for (int mi = 0; mi < 2; ++mi) {
            S[mi][ni] = MFMA(ah[mi], bh, S[mi][ni]);
            S[mi][ni] = MFMA(ah[mi], bl, S[mi][ni]);
            S[mi][ni] = MFMA(al[mi], bh, S[mi][ni]);
          }
        }
      }
    }
#pragma unroll
    for (int ni = 0; ni < 8; ++ni) {
      float il = invl[b * Tn + tt * 128 + ni * 16 + l15];
#pragma unroll
      for (int mi = 0; mi < 2; ++mi)
#pragma unroll
        for (int r = 0; r < 4; ++r) uacc[mi][r] += __expf(S[mi][ni][r]) * il;
    }
  }
#pragma unroll
  for (int mi = 0; mi < 2; ++mi)
#pragma unroll
    for (int r = 0; r < 4; ++r) {
      float v = uacc[mi][r];
      v += __shfl_xor(v, 1);
      v += __shfl_xor(v, 2);
      v += __shfl_xor(v, 4);
      v += __shfl_xor(v, 8);
      if (l15 == 0)
        prio[(size_t)b * CAPn + cBase + w * 32 + mi * 16 + g * 4 + r] =
            comb[b] + 0.1f * v;
    }
}

// rank init: unselected slots get Kn (k_newmem tests r < Kn)
__global__ void k_rankinit(int* __restrict__ rank) {
  rank[blockIdx.x * 256 + threadIdx.x] = Kn;
}

// Per-batch exact top-K selection + stable rank (jax top_k semantics).
__global__ __launch_bounds__(1024) void k_select(const float* __restrict__ prio,
                                                 int* __restrict__ rank) {
  const int b = blockIdx.x;
  const float* p = prio + (size_t)b * CAPn;
  __shared__ int hist[256];
  __shared__ unsigned long long s_pref;
  __shared__ int s_krem;
  __shared__ int s_cnt;
  __shared__ unsigned long long selk[Kn];
  const int tid = threadIdx.x;
  if (tid == 0) { s_pref = 0ull; s_krem = Kn; s_cnt = 0; }

#define KEYOF(c, kk)                                                         \
  {                                                                          \
    unsigned mb_ = __float_as_uint(p[(c)]);                                  \
    mb_ = (mb_ & 0x80000000u) ? ~mb_ : (mb_ | 0x80000000u);                  \
    (kk) = ((unsigned long long)mb_ << 32) | (unsigned)(0xFFFFFFFFu - (c));  \
  }

  __syncthreads();
  for (int pos = 56; pos >= 0; pos -= 8) {
    if (tid < 256) hist[tid] = 0;
    __syncthreads();
    unsigned long long pref = s_pref;
    unsigned long long maskhi = (pos == 56) ? 0ull : (~0ull << (pos + 8));
    for (int c = tid; c < CAPn; c += 1024) {
      unsigned long long k;
      KEYOF(c, k);
      if ((k & maskhi) == pref) atomicAdd(&hist[(int)((k >> pos) & 255)], 1);
    }
    __syncthreads();
    if (tid == 0) {
      int krem = s_krem;
      int d = 255;
      for (;; --d) {
        int h = hist[d];
        if (krem <= h || d == 0) break;
        krem -= h;
      }
      s_pref = pref | ((unsigned long long)d << pos);
      s_krem = krem;
    }
    __syncthreads();
  }
  unsigned long long T = s_pref;  // exact Kn-th largest key
  for (int c = tid; c < CAPn; c += 1024) {
    unsigned long long k;
    KEYOF(c, k);
    if (k >= T) {
      int idx = atomicAdd(&s_cnt, 1);
      selk[idx] = k;
    }
  }
  __syncthreads();
  unsigned long long mine = selk[tid];
  int r = 0;
  for (int j = 0; j < Kn; ++j) r += (selk[j] > mine) ? 1 : 0;
  int c = (int)(0xFFFFFFFFu - (unsigned)(mine & 0xFFFFFFFFull));
  rank[(size_t)b * CAPn + c] = r;
#undef KEYOF
}

// new_mem (bf16) = 0.99*mem + 0.0025 * sum_b (rank_b[c] < K ? values[b, rank_b[c], :] : 0)
__global__ void k_newmem(const float* __restrict__ mem, const float* __restrict__ values,
                         const int* __restrict__ rank, ush* __restrict__ nm) {
  int gid = blockIdx.x * 256 + threadIdx.x;
  int c = gid >> 7;
  int q = (gid & 127) << 2;
  f32x4 m = *(const f32x4*)&mem[(size_t)c * Dn + q];
  f32x4 acc = {0.f, 0.f, 0.f, 0.f};
#pragma unroll
  for (int b = 0; b < Bn; ++b) {
    int r = rank[(size_t)b * CAPn + c];
    if (r < Kn) acc += *(const f32x4*)&values[((size_t)b * Tn + r) * Dn + q];
  }
  f32x4 res = m * MOM + acc * RATE_B;
  s16x4 o;
#pragma unroll
  for (int j = 0; j < 4; ++j) o[j] = (short)bfrn(res[j]);
  *(s16x4*)&nm[(size_t)c * Dn + q] = o;
}

// nmT[d][c] = nm[c][d]
__global__ void k_nmT(const ush* __restrict__ nm, ush* __restrict__ nmT) {
  __shared__ ush tile[64][65];
  int cBase = blockIdx.x * 64, dBase = blockIdx.y * 64;
  int tid = threadIdx.x;
#pragma unroll
  for (int rr = 0; rr < 2; ++rr) {
    int idx = rr * 256 + tid;
    int row = idx >> 3, ch = idx & 7;
    s16x8 v = *(const s16x8*)&nm[(size_t)(cBase + row) * Dn + dBase + ch * 8];
#pragma unroll
    for (int j = 0; j < 8; ++j) tile[row][ch * 8 + j] = (ush)v[j];
  }
  __syncthreads();
#pragma unroll
  for (int rr = 0; rr < 2; ++rr) {
    int idx = rr * 256 + tid;
    int drow = idx >> 3, ch = idx & 7;
    s16x8 v;
#pragma unroll
    for (int j = 0; j < 8; ++j) v[j] = (short)tile[ch * 8 + j][drow];
    *(s16x8*)&nmT[(size_t)(dBase + drow) * CAPn + cBase + ch * 8] = v;
  }
}

// Fused attn, counted-vmcnt pipeline (T3+T4+T5), WAR-SAFE ordering:
// stage for phase p+2 is issued AFTER BAR(p). BAR(p) is preceded by every
// wave's lgkmcnt(0), so all phase-(p-1) ds_reads of the target buffer
// (p+2)%3 == (p-1)%3 have completed before the overwrite is issued.
// RAW side: uniform s_waitcnt vmcnt(2) before BAR -- the 2 newest outstanding
// loads are phase p+1's stage; the pair targeting phase p is complete.
// vmcnt never drains to 0 inside the loop; prefetch depth = 2 phases.
// Grid (8 cy, 32 qt), 8 waves, Q in regs.
// LDS 131KB: Ms[3][128][64] @0, Mt[3][128][64] @24576, Ps[128][128] @49152 (ush idx).
__global__ __launch_bounds__(512, 1) void k_attnout(
    const float* __restrict__ query, const ush* __restrict__ nm,
    const ush* __restrict__ nmT, ush* __restrict__ opart,
    float* __restrict__ zp2) {
  __shared__ ush lds[65536];
  __shared__ float zred[128];
  __shared__ float zacc[128];
  constexpr int LMS = 0, LMT = 24576, LPS = 49152;
  const int tid = threadIdx.x;
  const int lane = tid & 63, w = tid >> 6;
  const int l15 = lane & 15, g = lane >> 4;
  const int cy = blockIdx.x;
  const int qBase = blockIdx.y * 128;
  const int q = w * 16 + l15;
  const int r0 = tid >> 3, u0 = tid & 7;
  const int usw = (u0 ^ (r0 & 7)) << 3;

  auto stage_ms = [&](int buf, int cb_, int kk) {
    const ush* src = nm + (size_t)cb_ * Dn + kk * 64;
    gl16(&src[(size_t)r0 * Dn + usw], &lds[LMS + buf * 8192 + w * 512]);
    gl16(&src[(size_t)(r0 + 64) * Dn + usw], &lds[LMS + buf * 8192 + 4096 + w * 512]);
  };
  auto stage_mt = [&](int buf, int cb_, int u) {
    const ush* src = nmT + (size_t)((u >> 1) * 128) * CAPn + cb_ + (u & 1) * 64;
    gl16(&src[(size_t)r0 * CAPn + usw], &lds[LMT + buf * 8192 + w * 512]);
    gl16(&src[(size_t)(r0 + 64) * CAPn + usw], &lds[LMT + buf * 8192 + 4096 + w * 512]);
  };

  // Q fragments in registers: row qBase+q, full K=512, converted once.
  s16x8 qfr[16];
  {
    const float* qsrc = query + (size_t)(qBase + q) * Dn;
#pragma unroll
    for (int ks = 0; ks < 16; ++ks) {
      f32x4 a = *(const f32x4*)&qsrc[ks * 32 + g * 8];
      f32x4 b = *(const f32x4*)&qsrc[ks * 32 + g * 8 + 4];
      s16x8 h;
#pragma unroll
      for (int j = 0; j < 4; ++j) {
        h[j] = (short)bfrn(a[j]);
        h[4 + j] = (short)bfrn(b[j]);
      }
      qfr[ks] = h;
    }
  }

  f32x4 O[32];
#pragma unroll
  for (int i = 0; i < 32; ++i) O[i] = (f32x4){0.f, 0.f, 0.f, 0.f};
  if (tid < 128) zacc[tid] = 0.f;

  // pipeline prologue: stages for QK0, QK1 of ct=0 (4 gl16 outstanding)
  stage_ms(0, cy * 4096, 0);
  stage_ms(1, cy * 4096, 1);

  for (int ct = 0; ct < 32; ++ct) {
    const int cBase = cy * 4096 + ct * 128;
    const int cNext = cy * 4096 + ((ct + 1) & 31) * 128;  // wrap: valid addr, unused data

    // ---- QK phases kk=0..7: read Ms[kk%3]; stage issued post-BAR ----
    f32x4 S[8];
#pragma unroll
    for (int i = 0; i < 8; ++i) S[i] = (f32x4){0.f, 0.f, 0.f, 0.f};
#pragma unroll
    for (int kk = 0; kk < 8; ++kk) {
      WAITV2;
      WAITL0;
      BAR;
      if (kk < 6) stage_ms((kk + 2) % 3, cBase, kk + 2);
      else if (kk == 6) stage_mt(0, cBase, 0);
      else stage_mt(1, cBase, 1);
      __builtin_amdgcn_s_setprio(1);
#pragma unroll
      for (int ks2 = 0; ks2 < 2; ++ks2) {
#pragma unroll
        for (int mi = 0; mi < 8; ++mi) {
          int row = mi * 16 + l15;
          s16x8 am = *(const s16x8*)&lds[LMS + (kk % 3) * 8192 + row * 64 +
                                         (((ks2 * 4 + g) ^ (row & 7)) << 3)];
          S[mi] = MFMA(am, qfr[kk * 2 + ks2], S[mi]);
        }
      }
      __builtin_amdgcn_s_setprio(0);
    }

    // ---- P phase: exp(S*SCALE) -> Ps (unnormalized); z partial. No stage. ----
    float zl = 0.f;
#pragma unroll
    for (int mi = 0; mi < 8; ++mi) {
      s16x4 p;
#pragma unroll
      for (int r = 0; r < 4; ++r) {
        float e = __expf(S[mi][r] * SCALE);
        zl += e;
        p[r] = (short)bfrn(e);
      }
      int u16 = (mi * 2 + (g >> 1)) ^ l15;
      *(s16x4*)&lds[LPS + q * 128 + u16 * 8 + (g & 1) * 4] = p;
    }
    zl += __shfl_xor(zl, 16);
    zl += __shfl_xor(zl, 32);
    if (g == 0) zred[q] = zl;
    WAITL0;
    BAR;
    if (tid < 128) zacc[tid] += zred[tid];

    // ---- PV phases u=0..7: read Mt[u%3]; stage post-BAR (tail -> next ct Ms) ----
#pragma unroll
    for (int u = 0; u < 8; ++u) {
      WAITV2;
      WAITL0;
      BAR;
      if (u < 6) stage_mt((u + 2) % 3, cBase, u + 2);
      else if (u == 6) stage_ms(0, cNext, 0);
      else stage_ms(1, cNext, 1);
      __builtin_amdgcn_s_setprio(1);
      const int hh = u & 1;
#pragma unroll
      for (int kc = 0; kc < 2; ++kc) {
        int u16 = (hh * 8 + kc * 4 + g) ^ l15;
        s16x8 pb = *(const s16x8*)&lds[LPS + q * 128 + u16 * 8];
#pragma unroll
        for (int mi = 0; mi < 8; ++mi) {
          int row = mi * 16 + l15;
          s16x8 am = *(const s16x8*)&lds[LMT + (u % 3) * 8192 + row * 64 +
                                         (((kc * 4 + g) ^ (row & 7)) << 3)];
          O[(u >> 1) * 8 + mi] = MFMA(am, pb, O[(u >> 1) * 8 + mi]);
        }
      }
      __builtin_amdgcn_s_setprio(0);
    }
  }

  // ---- epilogue: drain everything (syncthreads => vmcnt(0)+lgkmcnt(0)),
  // z store + O transpose via LDS. Wrapped prefetch lands in Ms, unused. ----
  __syncthreads();
  if (tid < 128) zp2[(size_t)cy * ROWS + qBase + tid] = zacc[tid];
#pragma unroll
  for (int ds = 0; ds < 4; ++ds) {
    __syncthreads();
#pragma unroll
    for (int mi = 0; mi < 8; ++mi) {
      s16x4 ov;
#pragma unroll
      for (int r = 0; r < 4; ++r) ov[r] = (short)bfrn(O[ds * 8 + mi][r]);
      int u16 = (mi * 2 + (g >> 1)) ^ l15;
      *(s16x4*)&lds[LPS + q * 128 + u16 * 8 + (g & 1) * 4] = ov;
    }
    __syncthreads();
#pragma unroll
    for (int i = 0; i < 4; ++i) {
      int slot = i * 512 + tid;
      int qq = slot >> 4, u16 = slot & 15;
      s16x8 v = *(const s16x8*)&lds[LPS + qq * 128 + ((u16 ^ (qq & 15)) << 3)];
      *(s16x8*)&opart[((size_t)cy * ROWS + qBase + qq) * Dn + ds * 128 + u16 * 8] = v;
    }
  }
}

// out = (sum_cy opart[cy]) / (sum_cy zp2[cy]) per row
__global__ void k_merge(const ush* __restrict__ opart, const float* __restrict__ zp2,
                        float* __restrict__ out) {
  size_t i = ((size_t)blockIdx.x * 256 + threadIdx.x) * 4;
  int row = (int)(i >> 9);
  float z = 0.f;
#pragma unroll
  for (int cyy = 0; cyy < 8; ++cyy) z += zp2[(size_t)cyy * ROWS + row];
  float inv = 1.0f / z;
  f32x4 acc = {0.f, 0.f, 0.f, 0.f};
#pragma unroll
  for (int cyy = 0; cyy < 8; ++cyy) {
    s16x4 a = *(const s16x4*)&opart[(size_t)cyy * ROWS * Dn + i];
#pragma unroll
    for (int j = 0; j < 4; ++j) acc[j] += bff((ush)a[j]);
  }
#pragma unroll
  for (int j = 0; j < 4; ++j) acc[j] *= inv;
  *(f32x4*)&out[i] = acc;
}

extern "C" void kernel_launch(void* const* d_in, const int* in_sizes, int n_in,
                              void* d_out, int out_size, void* d_ws, size_t ws_size,
                              hipStream_t stream) {
  const float* keys = (const float*)d_in[0];
  const float* values = (const float*)d_in[1];
  const float* importance = (const float*)d_in[2];
  const float* query = (const float*)d_in[3];
  const float* mem = (const float*)d_in[4];
  char* wsb = (char*)d_ws;
  ush* nm    = (ush*)(wsb + OFF_NM);
  ush* nmT   = (ush*)(wsb + OFF_NMT);
  ush* mlo   = (ush*)(wsb + OFF_NM);   // alias (dead after k_usage)
  ush* mhi   = (ush*)(wsb + OFF_NMT);  // alias (dead after k_usage)
  ush* khi   = (ush*)(wsb + OFF_KHI);
  ush* klo   = (ush*)(wsb + OFF_KLO);
  ush* opart = (ush*)(wsb + OFF_OPART);
  float* zpart = (float*)(wsb + OFF_ZPART);
  float* prio  = (float*)(wsb + OFF_PRIO);
  int* rank    = (int*)(wsb + OFF_RANK);
  float* comb  = (float*)(wsb + OFF_COMB);
  float* zp2   = (float*)(wsb + OFF_ZP2);
  float* invl1 = (float*)(wsb + OFF_COMB + 64);
  float* out = (float*)d_out;

  k_combined<<<Bn, 256, 0, stream>>>(importance, comb);
  k_cvt_hilo<<<(ROWS * Dn / 4) / 256, 256, 0, stream>>>(keys, khi, klo);
  k_cvt_hilo<<<(CAPn * Dn / 4) / 256, 256, 0, stream>>>(mem, mhi, mlo);
  k_rowexp<<<CAPn / 64, 256, 0, stream>>>(mhi, khi, zpart);
  k_invl<<<ROWS / 256, 256, 0, stream>>>(zpart, invl1);
  k_usage<<<dim3(CAPn / 128, Bn), 256, 0, stream>>>(mhi, mlo, khi, klo, invl1, comb, prio);
  k_rankinit<<<(Bn * CAPn) / 256, 256, 0, stream>>>(rank);
  k_select<<<Bn, 1024, 0, stream>>>(prio, rank);
  k_newmem<<<(CAPn * Dn / 4) / 256, 256, 0, stream>>>(mem, values, rank, nm);
  k_nmT<<<dim3(CAPn / 64, Dn / 64), 256, 0, stream>>>(nm, nmT);
  k_attnout<<<dim3(8, ROWS / 128), 512, 0, stream>>>(query, nm, nmT, opart, zp2);
  k_merge<<<(ROWS * Dn / 4) / 256, 256, 0, stream>>>(opart, zp2, out);
}